// Round 10
// baseline (342.356 us; speedup 1.0000x reference)
//
#include <hip/hip_runtime.h>

// ---------------------------------------------------------------------------
// EncoderLayer: x -> MHA(entmax1.5) -> +LN -> FFN(mish) -> +LN
// B=8 S=1024 D=512 H=8 hd=64 F=2048.  bf16 MFMA GEMMs, fp32 accum/epilogues.
// Round 19: tau-deferred entmax, done right this time. entmax_tau = same
// compacted DPP solver but writes ONLY tau[row] (256 KB vs 131 MB of P
// rewrite). gemm_pv = the PROVEN sbuf PV structure (BM=256, 40 KiB LDS,
// 2 barriers/step - NOT R5's 80KiB dbuf) with fused p=max(z-tau,0)^2 in
// A-staging (reg-load -> transform -> ds_write; bit-identical math).
// R9 lesson logged: identical GEMM code swings +-17% across rounds; stop
// micro-tuning GEMM structure. Everything else byte-identical to R9.
// ---------------------------------------------------------------------------

typedef float f32x4 __attribute__((ext_vector_type(4)));
typedef float f32x2 __attribute__((ext_vector_type(2)));
typedef __bf16 b8 __attribute__((ext_vector_type(8)));

#define DEV static __device__ __forceinline__

DEV unsigned short f2bf(float f) {
  // gfx950: native cast -> v_cvt_pk_bf16_f32 (RNE); compiler pairs casts.
  return __builtin_bit_cast(unsigned short, (__bf16)f);
}
DEV float bf2f(unsigned short b) { return __uint_as_float(((unsigned)b) << 16); }

DEV float mishf(float x) {
  if (x > 20.f) return x;
  float e = __expf(x);
  float u = 1.f + e;
  u *= u;
  return x * ((u - 1.f) / (u + 1.f));
}

DEV void async16(const void* g, void* l) {
  __builtin_amdgcn_global_load_lds(
      (const __attribute__((address_space(1))) unsigned int*)g,
      (__attribute__((address_space(3))) unsigned int*)l, 16, 0, 0);
}

DEV int mbcnt64(unsigned long long m) {
  return __builtin_amdgcn_mbcnt_hi((unsigned)(m >> 32),
                                   __builtin_amdgcn_mbcnt_lo((unsigned)m, 0));
}

// --- DPP-based wave64 reductions (VALU for xor1..8, LDS only for 16/32) ----
template <int CTRL>
DEV float dppmov(float x) {
  return __builtin_bit_cast(
      float, __builtin_amdgcn_update_dpp(0, __builtin_bit_cast(int, x), CTRL,
                                         0xF, 0xF, true));
}
DEV float swz16(float x) {  // xor-16 within each 32-lane half
  return __builtin_bit_cast(
      float, __builtin_amdgcn_ds_swizzle(__builtin_bit_cast(int, x), 0x401F));
}
DEV float wave_sum(float x) {
  x += dppmov<0xB1>(x);    // quad_perm [1,0,3,2]  (xor 1)
  x += dppmov<0x4E>(x);    // quad_perm [2,3,0,1]  (xor 2)
  x += dppmov<0x141>(x);   // row_half_mirror      (xor 4 pattern)
  x += dppmov<0x140>(x);   // row_mirror           (xor 8 pattern)
  x += swz16(x);
  x += __shfl_xor(x, 32);
  return x;
}
DEV float wave_max(float x) {
  x = fmaxf(x, dppmov<0xB1>(x));
  x = fmaxf(x, dppmov<0x4E>(x));
  x = fmaxf(x, dppmov<0x141>(x));
  x = fmaxf(x, dppmov<0x140>(x));
  x = fmaxf(x, swz16(x));
  x = fmaxf(x, __shfl_xor(x, 32));
  return x;
}

// ---------------------------------------------------------------------------
// Generic MFMA GEMM:  C[M,N] = alpha * A[M,K] * Bt[N,K]^T (+bias) (+mish)
// Batched / split-K via blockIdx.z: off = (z/hdiv)*s1 + (z%hdiv)*s2.
// BK=64: LDS row = 8 groups of 8 bf16; slot s of row m holds group s^(m&7).
// Single-buffer, 2 barriers/K-step (proven optimum for this regime).
// ---------------------------------------------------------------------------
template <int WM, int WN, int EPI, bool OUTBF>
__global__ __launch_bounds__(256) void gemm_bt(
    const unsigned short* __restrict__ A, const unsigned short* __restrict__ Bt,
    const float* __restrict__ bias, void* __restrict__ Cp,
    int K, int lda, int ldb, int ldc,
    long sA1, long sA2, long sB1, long sB2, long sC1, long sC2,
    int hdiv, float alpha) {
  constexpr int BM = WM * 64, BN = WN * 64;
  constexpr int NA = WM * 2, NB = WN * 2;  // staging slots per thread
  __shared__ unsigned short smA[BM * 64];
  __shared__ unsigned short smB[BN * 64];

  const int tid = threadIdx.x;
  const int lane = tid & 63;
  const int z = blockIdx.z;
  const long zi = z / hdiv, zr = z % hdiv;
  const unsigned short* Ab = A + zi * sA1 + zr * sA2 + (long)blockIdx.x * BM * lda;
  const unsigned short* Bb = Bt + zi * sB1 + zr * sB2 + (long)blockIdx.y * BN * ldb;

  int siA[NA];
  const unsigned short* gA[NA];
#pragma unroll
  for (int q = 0; q < NA; ++q) {
    int si = q * 256 + tid;
    int m = si >> 3, s = si & 7, g = s ^ (m & 7);
    siA[q] = si;
    gA[q] = Ab + (long)m * lda + g * 8;
  }
  int siB[NB];
  const unsigned short* gB[NB];
#pragma unroll
  for (int q = 0; q < NB; ++q) {
    int si = q * 256 + tid;
    int m = si >> 3, s = si & 7, g = s ^ (m & 7);
    siB[q] = si;
    gB[q] = Bb + (long)m * ldb + g * 8;
  }

  const int w = tid >> 6;
  const int wr = w / WN, wc = w % WN;
  const int fm = lane & 15, fg = lane >> 4;

  int aOff[4][2], bOff[4][2];
#pragma unroll
  for (int i = 0; i < 4; ++i)
#pragma unroll
    for (int ks = 0; ks < 2; ++ks) {
      int m = wr * 64 + i * 16 + fm;
      aOff[i][ks] = (m * 8 + ((ks * 4 + fg) ^ (fm & 7))) * 8;
      int n = wc * 64 + i * 16 + fm;
      bOff[i][ks] = (n * 8 + ((ks * 4 + fg) ^ (fm & 7))) * 8;
    }

  f32x4 acc[4][4];
#pragma unroll
  for (int i = 0; i < 4; ++i)
#pragma unroll
    for (int j = 0; j < 4; ++j) acc[i][j] = (f32x4){0.f, 0.f, 0.f, 0.f};

  for (int k0 = 0; k0 < K; k0 += 64) {
    __syncthreads();
#pragma unroll
    for (int q = 0; q < NA; ++q) async16(gA[q] + k0, (void*)&smA[siA[q] * 8]);
#pragma unroll
    for (int q = 0; q < NB; ++q) async16(gB[q] + k0, (void*)&smB[siB[q] * 8]);
    __syncthreads();  // implies vmcnt(0): staging complete

#pragma unroll
    for (int ks = 0; ks < 2; ++ks) {
      b8 aF[4], bF[4];
#pragma unroll
      for (int i = 0; i < 4; ++i) aF[i] = *(const b8*)&smA[aOff[i][ks]];
#pragma unroll
      for (int j = 0; j < 4; ++j) bF[j] = *(const b8*)&smB[bOff[j][ks]];
#pragma unroll
      for (int i = 0; i < 4; ++i)
#pragma unroll
        for (int j = 0; j < 4; ++j)
          acc[i][j] = __builtin_amdgcn_mfma_f32_16x16x32_bf16(aF[i], bF[j], acc[i][j], 0, 0, 0);
    }
  }

  const long cbase = zi * sC1 + zr * sC2;
  const int row0 = blockIdx.x * BM + wr * 64 + fg * 4;
  const int col0 = blockIdx.y * BN + wc * 64 + fm;
#pragma unroll
  for (int i = 0; i < 4; ++i) {
#pragma unroll
    for (int j = 0; j < 4; ++j) {
      const int col = col0 + j * 16;
      float bv = (EPI >= 1) ? bias[col] : 0.f;
#pragma unroll
      for (int r = 0; r < 4; ++r) {
        const int row = row0 + i * 16 + r;
        float v = acc[i][j][r] * alpha + bv;
        if (EPI == 2) v = mishf(v);
        const long idx = cbase + (long)row * ldc + col;
        if constexpr (OUTBF)
          ((unsigned short*)Cp)[idx] = f2bf(v);
        else
          ((float*)Cp)[idx] = v;
      }
    }
  }
}

// ---------------------------------------------------------------------------
// Scores standalone: P[z][q][k] = (Q K^T)/16, K=64 baked (single K-step).
// Q direct-to-register; only K staged via async16 (16 KiB LDS). One barrier.
// ---------------------------------------------------------------------------
__global__ __launch_bounds__(256) void gemm_scores(
    const unsigned short* __restrict__ QKV, unsigned short* __restrict__ P) {
  __shared__ unsigned short smB[128 * 64];  // K-rows tile, gemm format

  const int tid = threadIdx.x, lane = tid & 63, w = tid >> 6;
  const int wr = w >> 1, wc = w & 1;
  const int fm = lane & 15, fg = lane >> 4;
  const int z = blockIdx.z, b = z >> 3, h = z & 7;
  const long qrow0 = (long)b * 1024 + blockIdx.x * 128;
  const long krow0 = (long)b * 1024 + blockIdx.y * 128;

#pragma unroll
  for (int q = 0; q < 4; ++q) {
    int si = q * 256 + tid;
    int m = si >> 3, s = si & 7, g = s ^ (m & 7);
    async16(QKV + (krow0 + m) * 1536 + 512 + h * 64 + g * 8, (void*)&smB[si * 8]);
  }

  b8 aQ[4][2];
#pragma unroll
  for (int i = 0; i < 4; ++i) {
    const unsigned short* qp =
        QKV + (qrow0 + wr * 64 + i * 16 + fm) * 1536 + h * 64 + fg * 8;
    aQ[i][0] = *(const b8*)qp;
    aQ[i][1] = *(const b8*)(qp + 32);
  }

  __syncthreads();  // implies vmcnt(0): staging + Q loads complete

  f32x4 acc[4][4];
#pragma unroll
  for (int i = 0; i < 4; ++i)
#pragma unroll
    for (int j = 0; j < 4; ++j) acc[i][j] = (f32x4){0.f, 0.f, 0.f, 0.f};

#pragma unroll
  for (int ks = 0; ks < 2; ++ks) {
    b8 bF[4];
#pragma unroll
    for (int j = 0; j < 4; ++j) {
      int n = wc * 64 + j * 16 + fm;
      bF[j] = *(const b8*)&smB[(n * 8 + ((ks * 4 + fg) ^ (fm & 7))) * 8];
    }
#pragma unroll
    for (int i = 0; i < 4; ++i)
#pragma unroll
      for (int j = 0; j < 4; ++j)
        acc[i][j] = __builtin_amdgcn_mfma_f32_16x16x32_bf16(aQ[i][ks], bF[j], acc[i][j], 0, 0, 0);
  }

  unsigned short* Pb = P + (long)z * 1024 * 1024;
  const int row0 = blockIdx.x * 128 + wr * 64 + fg * 4;
  const int col0 = blockIdx.y * 128 + wc * 64 + fm;
#pragma unroll
  for (int i = 0; i < 4; ++i)
#pragma unroll
    for (int j = 0; j < 4; ++j)
#pragma unroll
      for (int r = 0; r < 4; ++r)
        Pb[(long)(row0 + i * 16 + r) * 1024 + col0 + j * 16] =
            f2bf(acc[i][j][r] * 0.0625f);
}

// ---------------------------------------------------------------------------
// PV with fused entmax transform: attn = (max(z - tau_row, 0)^2) @ V.
// EXACT proven PV structure (BM=256 BN=64, sbuf 40 KiB, 2 barriers/K-step,
// grid (4,1,64), 256 threads). Only the A-staging path changes: reg-load A
// (issued first), async16 B, transform+ds_write (bit-identical math to the
// old entmax_rows epilogue), barrier, compute.
// ---------------------------------------------------------------------------
__global__ __launch_bounds__(256) void gemm_pv(
    const unsigned short* __restrict__ P, const unsigned short* __restrict__ Vt,
    const float* __restrict__ Tau, unsigned short* __restrict__ attn) {
  __shared__ unsigned short smA[256 * 64];  // 32 KiB
  __shared__ unsigned short smB[64 * 64];   // 8 KiB

  const int tid = threadIdx.x, lane = tid & 63, w = tid >> 6;
  const int fm = lane & 15, fg = lane >> 4;
  const int z = blockIdx.z;
  const long SS = 1024L * 1024L;
  const unsigned short* Ab = P + (long)z * SS + (long)blockIdx.x * 256 * 1024;
  const unsigned short* Bb = Vt + (long)z * 64 * 1024;
  const float* Tb = Tau + (long)z * 1024 + blockIdx.x * 256;

  int siA[8];
  const unsigned short* gA[8];
  float tq[8];
#pragma unroll
  for (int q = 0; q < 8; ++q) {
    int si = q * 256 + tid;
    int m = si >> 3, s = si & 7, g = s ^ (m & 7);
    siA[q] = si;
    gA[q] = Ab + (long)m * 1024 + g * 8;
    tq[q] = Tb[m];
  }
  int siB[2];
  const unsigned short* gB[2];
#pragma unroll
  for (int q = 0; q < 2; ++q) {
    int si = q * 256 + tid;
    int m = si >> 3, s = si & 7, g = s ^ (m & 7);
    siB[q] = si;
    gB[q] = Bb + (long)m * 1024 + g * 8;
  }

  int aOff[4][2], bOff[4][2];
#pragma unroll
  for (int i = 0; i < 4; ++i)
#pragma unroll
    for (int ks = 0; ks < 2; ++ks) {
      int m = w * 64 + i * 16 + fm;  // wr = w, wc = 0
      aOff[i][ks] = (m * 8 + ((ks * 4 + fg) ^ (fm & 7))) * 8;
      int n = i * 16 + fm;
      bOff[i][ks] = (n * 8 + ((ks * 4 + fg) ^ (fm & 7))) * 8;
    }

  f32x4 acc[4][4];
#pragma unroll
  for (int i = 0; i < 4; ++i)
#pragma unroll
    for (int j = 0; j < 4; ++j) acc[i][j] = (f32x4){0.f, 0.f, 0.f, 0.f};

  union AB { b8 v; unsigned short u[8]; };
  for (int k0 = 0; k0 < 1024; k0 += 64) {
    __syncthreads();
    AB areg[8];
#pragma unroll
    for (int q = 0; q < 8; ++q) areg[q].v = *(const b8*)(gA[q] + k0);  // A first
#pragma unroll
    for (int q = 0; q < 2; ++q) async16(gB[q] + k0, (void*)&smB[siB[q] * 8]);
#pragma unroll
    for (int q = 0; q < 8; ++q) {  // transform + ds_write (waits A loads only)
      AB o;
#pragma unroll
      for (int e = 0; e < 8; ++e) {
        float h = fmaxf(bf2f(areg[q].u[e]) - tq[q], 0.f);
        o.u[e] = f2bf(h * h);
      }
      *(b8*)&smA[siA[q] * 8] = o.v;
    }
    __syncthreads();  // drains B async16 + ds_writes

#pragma unroll
    for (int ks = 0; ks < 2; ++ks) {
      b8 aF[4], bF[4];
#pragma unroll
      for (int i = 0; i < 4; ++i) aF[i] = *(const b8*)&smA[aOff[i][ks]];
#pragma unroll
      for (int j = 0; j < 4; ++j) bF[j] = *(const b8*)&smB[bOff[j][ks]];
#pragma unroll
      for (int i = 0; i < 4; ++i)
#pragma unroll
        for (int j = 0; j < 4; ++j)
          acc[i][j] = __builtin_amdgcn_mfma_f32_16x16x32_bf16(aF[i], bF[j], acc[i][j], 0, 0, 0);
    }
  }

  const long cbase = (long)(z >> 3) * 1024 * 512 + (z & 7) * 64;
  const int row0 = blockIdx.x * 256 + w * 64 + fg * 4;
#pragma unroll
  for (int i = 0; i < 4; ++i)
#pragma unroll
    for (int j = 0; j < 4; ++j) {
      const int col = fm + j * 16;
#pragma unroll
      for (int r = 0; r < 4; ++r) {
        const int row = row0 + i * 16 + r;
        attn[cbase + (long)row * 512 + col] = f2bf(acc[i][j][r]);
      }
    }
}

// ---------------------------------------------------------------------------
// FFN1 standalone: hb = mish(x1b @ W1t^T + b1), dbuf, 1 barrier/K-step.
// ---------------------------------------------------------------------------
__global__ __launch_bounds__(256) void gemm_ffn1(
    const unsigned short* __restrict__ A, const unsigned short* __restrict__ Bt,
    const float* __restrict__ bias, unsigned short* __restrict__ C) {
  __shared__ unsigned short smA[2 * 128 * 64];
  __shared__ unsigned short smB[2 * 128 * 64];

  const int tid = threadIdx.x;
  const int lane = tid & 63;
  const unsigned short* Ab = A + (long)blockIdx.x * 128 * 512;
  const unsigned short* Bb = Bt + (long)blockIdx.y * 128 * 512;

  int siA[4], siB[4];
  const unsigned short* gA[4];
  const unsigned short* gB[4];
#pragma unroll
  for (int q = 0; q < 4; ++q) {
    int si = q * 256 + tid;
    int m = si >> 3, s = si & 7, g = s ^ (m & 7);
    siA[q] = si;
    siB[q] = si;
    gA[q] = Ab + (long)m * 512 + g * 8;
    gB[q] = Bb + (long)m * 512 + g * 8;
  }

  const int w = tid >> 6;
  const int wr = w >> 1, wc = w & 1;
  const int fm = lane & 15, fg = lane >> 4;

  int aOff[4][2], bOff[4][2];
#pragma unroll
  for (int i = 0; i < 4; ++i)
#pragma unroll
    for (int ks = 0; ks < 2; ++ks) {
      int m = wr * 64 + i * 16 + fm;
      aOff[i][ks] = (m * 8 + ((ks * 4 + fg) ^ (fm & 7))) * 8;
      int n = wc * 64 + i * 16 + fm;
      bOff[i][ks] = (n * 8 + ((ks * 4 + fg) ^ (fm & 7))) * 8;
    }

  f32x4 acc[4][4];
#pragma unroll
  for (int i = 0; i < 4; ++i)
#pragma unroll
    for (int j = 0; j < 4; ++j) acc[i][j] = (f32x4){0.f, 0.f, 0.f, 0.f};

  auto stage = [&](int buf, int k0) {
    unsigned short* dA = smA + buf * (128 * 64);
    unsigned short* dB = smB + buf * (128 * 64);
#pragma unroll
    for (int q = 0; q < 4; ++q) async16(gA[q] + k0, (void*)&dA[siA[q] * 8]);
#pragma unroll
    for (int q = 0; q < 4; ++q) async16(gB[q] + k0, (void*)&dB[siB[q] * 8]);
  };
  auto compute = [&](int buf) {
    const unsigned short* sA = smA + buf * (128 * 64);
    const unsigned short* sB = smB + buf * (128 * 64);
#pragma unroll
    for (int ks = 0; ks < 2; ++ks) {
      b8 aF[4], bF[4];
#pragma unroll
      for (int i = 0; i < 4; ++i) aF[i] = *(const b8*)&sA[aOff[i][ks]];
#pragma unroll
      for (int j = 0; j < 4; ++j) bF[j] = *(const b8*)&sB[bOff[j][ks]];
#pragma unroll
      for (int i = 0; i < 4; ++i)
#pragma unroll
        for (int j = 0; j < 4; ++j)
          acc[i][j] = __builtin_amdgcn_mfma_f32_16x16x32_bf16(aF[i], bF[j], acc[i][j], 0, 0, 0);
    }
  };

  stage(0, 0);
  __syncthreads();
  int cur = 0;
  for (int k0 = 64; k0 < 512; k0 += 64) {
    stage(cur ^ 1, k0);
    compute(cur);
    __syncthreads();
    cur ^= 1;
  }
  compute(cur);

  const int row0 = blockIdx.x * 128 + wr * 64 + fg * 4;
  const int col0 = blockIdx.y * 128 + wc * 64 + fm;
#pragma unroll
  for (int i = 0; i < 4; ++i) {
#pragma unroll
    for (int j = 0; j < 4; ++j) {
      const int col = col0 + j * 16;
      const float bv = bias[col];
#pragma unroll
      for (int r = 0; r < 4; ++r) {
        const int row = row0 + i * 16 + r;
        C[(long)row * 2048 + col] = f2bf(mishf(acc[i][j][r] + bv));
      }
    }
  }
}

// ---------------------------------------------------------------------------
// entmax 1.5 tau solve over rows of 1024 (bf16 scores). One wave per row.
// Candidate compaction + DPP reductions. Writes ONLY tau[row]; the transform
// p=max(z-tau,0)^2 is applied inside gemm_pv (bit-identical math).
// ---------------------------------------------------------------------------
template <int NC>
DEV float solve_tau(const f32x2* zc, float tau) {
  int kprev = -1;
  const f32x2 zero2 = (f32x2){0.f, 0.f};
  for (int it = 0; it < 12; ++it) {
    const f32x2 t2 = (f32x2){tau, tau};
    f32x2 s1v = zero2, s2v = zero2;
    int k = 0;
#pragma unroll
    for (int i = 0; i < NC; ++i) {
      f32x2 h = zc[i] - t2;
      k += __popcll(__ballot(h.x > 0.f));
      k += __popcll(__ballot(h.y > 0.f));
      f32x2 hp = __builtin_elementwise_max(h, zero2);
      s1v += hp;
      s2v += hp * hp;
    }
    float s1 = wave_sum(s1v.x + s1v.y);
    float s2 = wave_sum(s2v.x + s2v.y);
    if (k == kprev) break;  // support fixed point -> tau exact (wave-uniform)
    kprev = k;
    float kf = (float)k;
    float disc = fmaxf(fmaf(s1, s1, -kf * (s2 - 1.f)), 0.f);
    tau += (s1 - __builtin_sqrtf(disc)) / kf;
  }
  return tau;
}

DEV float solve_tau_lds(const float* cw, int nch, int lane, float tau) {
  int kprev = -1;
  const f32x2 zero2 = (f32x2){0.f, 0.f};
  for (int it = 0; it < 12; ++it) {
    const f32x2 t2 = (f32x2){tau, tau};
    f32x2 s1v = zero2, s2v = zero2;
    int k = 0;
    for (int c = 0; c < nch; ++c) {
      f32x2 h = *(const f32x2*)&cw[c * 128 + lane * 2] - t2;
      k += __popcll(__ballot(h.x > 0.f));
      k += __popcll(__ballot(h.y > 0.f));
      f32x2 hp = __builtin_elementwise_max(h, zero2);
      s1v += hp;
      s2v += hp * hp;
    }
    float s1 = wave_sum(s1v.x + s1v.y);
    float s2 = wave_sum(s2v.x + s2v.y);
    if (k == kprev) break;
    kprev = k;
    float kf = (float)k;
    float disc = fmaxf(fmaf(s1, s1, -kf * (s2 - 1.f)), 0.f);
    tau += (s1 - __builtin_sqrtf(disc)) / kf;
  }
  return tau;
}

__global__ __launch_bounds__(256) void entmax_tau(const unsigned short* __restrict__ P,
                                                  float* __restrict__ T) {
  const int tid = threadIdx.x, lane = tid & 63, wv = tid >> 6;
  const long row = (long)blockIdx.x * 4 + wv;
  const unsigned short* p = P + row * 1024;
  __shared__ float cand[4][1024];  // per-wave candidate buffer (16 KiB)

  union { uint4 v; unsigned short u[8]; } a, b;
  a.v = *(const uint4*)(p + lane * 16);
  b.v = *(const uint4*)(p + lane * 16 + 8);
  f32x2 zp[8];
#pragma unroll
  for (int i = 0; i < 4; ++i) {
    zp[i] = (f32x2){bf2f(a.u[2 * i]), bf2f(a.u[2 * i + 1])};
    zp[4 + i] = (f32x2){bf2f(b.u[2 * i]), bf2f(b.u[2 * i + 1])};
  }

  f32x2 mv = zp[0];
#pragma unroll
  for (int i = 1; i < 8; ++i) mv = __builtin_elementwise_max(mv, zp[i]);
  float m = wave_max(fmaxf(mv.x, mv.y));

  const float thr = m - 1.f;
  float* cw = cand[wv];

  // compact candidates (z > thr) into cw[0..base)
  int base = 0;
#pragma unroll
  for (int i = 0; i < 8; ++i) {
    unsigned long long mx = __ballot(zp[i].x > thr);
    if (zp[i].x > thr) cw[base + mbcnt64(mx)] = zp[i].x;
    base += __popcll(mx);
    unsigned long long my = __ballot(zp[i].y > thr);
    if (zp[i].y > thr) cw[base + mbcnt64(my)] = zp[i].y;
    base += __popcll(my);
  }

  // pad to a multiple of 128 with a value that never contributes
  const int nch = (base + 127) >> 7;  // 1..8 chunks of 128
  for (int i = base + lane; i < nch * 128; i += 64) cw[i] = -1e30f;

  float tau;
  if (nch == 1) {
    f32x2 zc[1];
    zc[0] = *(const f32x2*)&cw[lane * 2];
    tau = solve_tau<1>(zc, thr);
  } else if (nch == 2) {
    f32x2 zc[2];
    zc[0] = *(const f32x2*)&cw[lane * 2];
    zc[1] = *(const f32x2*)&cw[128 + lane * 2];
    tau = solve_tau<2>(zc, thr);
  } else {
    tau = solve_tau_lds(cw, nch, lane, thr);
  }

  if (lane == 0) T[row] = tau;
}

// ---------------------------------------------------------------------------
// Merged prep: x cast + 6 weight transposes + bias concat in ONE launch.
// ---------------------------------------------------------------------------
__global__ __launch_bounds__(256) void prep_all(
    const float* __restrict__ x, unsigned short* __restrict__ xb,
    const float* __restrict__ Wq, const float* __restrict__ Wk,
    const float* __restrict__ Wv, const float* __restrict__ Wo,
    const float* __restrict__ W1, const float* __restrict__ W2,
    unsigned short* __restrict__ Wqkvt, unsigned short* __restrict__ Wot,
    unsigned short* __restrict__ W1t, unsigned short* __restrict__ W2t,
    const float* __restrict__ bq, const float* __restrict__ bk,
    const float* __restrict__ bv, float* __restrict__ bqkv) {
  __shared__ float t[32][33];
  const int bid = blockIdx.x, tid = threadIdx.x;

  if (bid < 4096) {  // cast x -> bf16, 4 elems/thread
    long i = ((long)bid * 256 + tid) * 4;
    float4 v = *(const float4*)&x[i];
    uint2 pk;
    pk.x = (unsigned)f2bf(v.x) | ((unsigned)f2bf(v.y) << 16);
    pk.y = (unsigned)f2bf(v.z) | ((unsigned)f2bf(v.w) << 16);
    *(uint2*)&xb[i] = pk;
    return;
  }

  const float* in;
  unsigned short* out;
  int ldi, ldo, bx, by;
  if (bid < 5120) {
    int t4 = (bid - 4096) >> 8, local = (bid - 4096) & 255;
    const float* ins[4] = {Wq, Wk, Wv, Wo};
    unsigned short* outs[4] = {Wqkvt, Wqkvt + 512 * 512, Wqkvt + 2 * 512 * 512, Wot};
    in = ins[t4];
    out = outs[t4];
    ldi = 512;
    ldo = 512;
    bx = local & 15;
    by = local >> 4;
  } else if (bid < 6144) {
    int local = bid - 5120;  // W1 [512][2048] -> W1t [2048][512]
    in = W1;
    out = W1t;
    ldi = 2048;
    ldo = 512;
    bx = local & 63;
    by = local >> 6;
  } else if (bid < 7168) {
    int local = bid - 6144;  // W2 [2048][512] -> W2t [512][2048]
    in = W2;
    out = W2t;
    ldi = 512;
    ldo = 2048;
    bx = local & 15;
    by = local >> 4;
  } else {  // concat biases
    int i = (bid - 7168) * 256 + tid;
    if (i < 512) bqkv[i] = bq[i];
    else if (i < 1024) bqkv[i] = bk[i - 512];
    else if (i < 1536) bqkv[i] = bv[i - 1024];
    return;
  }

  const int tx = tid & 31, ty = tid >> 5;
  const int r0 = by * 32, c0 = bx * 32;
#pragma unroll
  for (int q = 0; q < 4; ++q) {
    int r = ty + q * 8;
    t[r][tx] = in[(long)(r0 + r) * ldi + c0 + tx];
  }
  __syncthreads();
#pragma unroll
  for (int q = 0; q < 4; ++q) {
    int r = ty + q * 8;
    out[(long)(c0 + r) * ldo + r0 + tx] = f2bf(t[tx][r]);
  }
}

// bf16 batched transpose (for V -> V^T per (b,h))
__global__ __launch_bounds__(256) void transpose_b2b(const unsigned short* __restrict__ in,
                                                     unsigned short* __restrict__ out,
                                                     int ldi, int ldo, long i1, long i2,
                                                     long o1, long o2, int hdiv) {
  __shared__ unsigned short t[32][33];
  const int z = blockIdx.z;
  in += (long)(z / hdiv) * i1 + (long)(z % hdiv) * i2;
  out += (long)(z / hdiv) * o1 + (long)(z % hdiv) * o2;
  const int tx = threadIdx.x & 31, ty = threadIdx.x >> 5;
  const int r0 = blockIdx.y * 32, c0 = blockIdx.x * 32;
#pragma unroll
  for (int q = 0; q < 4; ++q) {
    int r = ty + q * 8;
    t[r][tx] = in[(long)(r0 + r) * ldi + c0 + tx];
  }
  __syncthreads();
#pragma unroll
  for (int q = 0; q < 4; ++q) {
    int r = ty + q * 8;
    out[(long)(c0 + r) * ldo + r0 + tx] = t[tx][r];
  }
}

// ---------------------------------------------------------------------------
// out = xin + LayerNorm(sum_j y[j*ystr] + ybias)*g + be   (row 512)
// ---------------------------------------------------------------------------
template <bool WB, int NS>
__global__ __launch_bounds__(256) void ln_res(const float* __restrict__ xin,
                                              const float* __restrict__ y, long ystr,
                                              const float* __restrict__ ybias,
                                              const float* __restrict__ g,
                                              const float* __restrict__ be,
                                              float* __restrict__ xo,
                                              unsigned short* __restrict__ xob) {
  const int row = blockIdx.x, tid = threadIdx.x, lane = tid & 63, wv = tid >> 6;
  const long base = (long)row * 512 + tid * 2;
  const int c = tid * 2;
  float2 v = *(const float2*)&y[base];
#pragma unroll
  for (int j = 1; j < NS; ++j) {
    float2 u = *(const float2*)&y[base + j * ystr];
    v.x += u.x;
    v.y += u.y;
  }
  v.x += ybias[c];
  v.y += ybias[c + 1];
  float s1 = wave_sum(v.x + v.y);
  float s2 = wave_sum(v.x * v.x + v.y * v.y);
  __shared__ float red[4][2];
  if (lane == 0) {
    red[wv][0] = s1;
    red[wv][1] = s2;
  }
  __syncthreads();
  s1 = red[0][0] + red[1][0] + red[2][0] + red[3][0];
  s2 = red[0][1] + red[1][1] + red[2][1] + red[3][1];
  const float mu = s1 * (1.f / 512.f);
  const float rstd = rsqrtf(s2 * (1.f / 512.f) - mu * mu + 1e-5f);
  float2 xv = *(const float2*)&xin[base];
  float o0 = xv.x + (v.x - mu) * rstd * g[c] + be[c];
  float o1 = xv.y + (v.y - mu) * rstd * g[c + 1] + be[c + 1];
  float2 ov;
  ov.x = o0;
  ov.y = o1;
  *(float2*)&xo[base] = ov;
  if constexpr (WB) {
    unsigned pk = (unsigned)f2bf(o0) | ((unsigned)f2bf(o1) << 16);
    *(unsigned*)&xob[base] = pk;
  }
}

// ---------------------------------------------------------------------------
extern "C" void kernel_launch(void* const* d_in, const int* in_sizes, int n_in,
                              void* d_out, int out_size, void* d_ws, size_t ws_size,
                              hipStream_t stream) {
  const int B = 8, S = 1024, D = 512, H = 8, F = 2048;
  const int BS = B * S;  // 8192 rows
  const int N3 = 3 * D;  // 1536

  const float* x = (const float*)d_in[0];
  const float* Wq = (const float*)d_in[1];
  const float* bq = (const float*)d_in[2];
  const float* Wk = (const float*)d_in[3];
  const float* bk = (const float*)d_in[4];
  const float* Wv = (const float*)d_in[5];
  const float* bv = (const float*)d_in[6];
  const float* Wo = (const float*)d_in[7];
  const float* bo = (const float*)d_in[8];
  const float* g1 = (const float*)d_in[9];
  const float* be1 = (const float*)d_in[10];
  const float* W1 = (const float*)d_in[11];
  const float* b1 = (const float*)d_in[12];
  const float* W2 = (const float*)d_in[13];
  const float* b2 = (const float*)d_in[14];
  const float* g2 = (const float*)d_in[15];
  const float* be2 = (const float*)d_in[16];
  float* out = (float*)d_out;

  char* w = (char*)d_ws;
  size_t off = 0;
  auto alloc = [&](size_t bytes) -> void* {
    void* p = w + off;
    off += bytes;
    off = (off + 255) & ~(size_t)255;
    return p;
  };

  unsigned short* xb = (unsigned short*)alloc((size_t)BS * D * 2);
  unsigned short* Wqkvt = (unsigned short*)alloc((size_t)N3 * D * 2);
  unsigned short* Wot = (unsigned short*)alloc((size_t)D * D * 2);
  unsigned short* W1t = (unsigned short*)alloc((size_t)F * D * 2);
  unsigned short* W2t = (unsigned short*)alloc((size_t)D * F * 2);
  float* bqkv = (float*)alloc((size_t)N3 * 4);
  unsigned short* QKVb = (unsigned short*)alloc((size_t)BS * N3 * 2);
  unsigned short* Vt = (unsigned short*)alloc((size_t)BS * D * 2);
  unsigned short* attn = (unsigned short*)alloc((size_t)BS * D * 2);
  unsigned short* P = (unsigned short*)alloc((size_t)B * H * S * S * 2);  // 128 MiB
  float* Tau = (float*)alloc((size_t)B * H * S * 4);                      // 256 KiB
  float* x1 = (float*)alloc((size_t)BS * D * 4);
  unsigned short* hb = (unsigned short*)alloc((size_t)BS * F * 2);
  unsigned short* x1b = xb;   // reuse: xb dead after QKV GEMM
  float* yp = (float*)P;      // reuse: P dead after PV GEMM
  const long PSTR = (long)BS * D;

  // 1) merged prep: cast x, transpose all weights, concat qkv bias
  prep_all<<<7174, 256, 0, stream>>>(x, xb, Wq, Wk, Wv, Wo, W1, W2,
                                     Wqkvt, Wot, W1t, W2t, bq, bk, bv, bqkv);

  // 2) merged QKV projection: [8192][1536] bf16
  gemm_bt<2, 2, 1, true><<<dim3(BS / 128, N3 / 128, 1), 256, 0, stream>>>(
      xb, Wqkvt, bqkv, QKVb, D, D, D, N3, 0, 0, 0, 0, 0, 0, 1, 1.f);

  // 3) V -> Vt[(b,h), d, s]
  transpose_b2b<<<dim3(2, 32, 64), 256, 0, stream>>>(
      QKVb + 1024, Vt, N3, S, (long)S * N3, 64, (long)8 * 64 * S, (long)64 * S, 8);

  // 4) scores z = (Q K^T)/16 -> P bf16 (standalone, K=64 baked, Q-in-reg)
  gemm_scores<<<dim3(S / 128, S / 128, B * H), 256, 0, stream>>>(QKVb, P);

  // 5) entmax-1.5 tau per row (tau only; transform fused into PV)
  entmax_tau<<<(B * H * S) / 4, 256, 0, stream>>>(P, Tau);

  // 6) attn = max(z - tau, 0)^2 @ V  (fused transform, proven sbuf structure)
  gemm_pv<<<dim3(S / 256, 1, B * H), 256, 0, stream>>>(P, Vt, Tau, attn);

  // 7) y = attn @ Wo, split-K x2 (bias folded into ln_res)
  gemm_bt<2, 2, 0, false><<<dim3(BS / 128, D / 128, 2), 256, 0, stream>>>(
      attn, Wot, nullptr, yp, D / 2, D, D, D, 0, D / 2, 0, D / 2, 0, PSTR, 2, 1.f);

  // 8) x1 = x + LN(y0+y1+bo)*g1 + be1
  ln_res<true, 2><<<BS, 256, 0, stream>>>(x, yp, PSTR, bo, g1, be1, x1, x1b);

  // 9) h = mish(x1 @ W1 + b1) (bf16) - standalone dbuf kernel
  gemm_ffn1<<<dim3(BS / 128, F / 128, 1), 256, 0, stream>>>(x1b, W1t, b1, hb);

  // 10) y2 = h @ W2, split-K x2 (K-chunks of 1024)
  gemm_bt<2, 2, 0, false><<<dim3(BS / 128, D / 128, 2), 256, 0, stream>>>(
      hb, W2t, nullptr, yp, F / 2, F, F, D, 0, F / 2, 0, F / 2, 0, PSTR, 2, 1.f);

  // 11) out = x1 + LN(y0+y1+b2)*g2 + be2
  ln_res<false, 2><<<BS, 256, 0, stream>>>(x1, yp, PSTR, b2, g2, be2, out, nullptr);
}

// Round 11
// 337.128 us; speedup vs baseline: 1.0155x; 1.0155x over previous
//
#include <hip/hip_runtime.h>

// ---------------------------------------------------------------------------
// EncoderLayer: x -> MHA(entmax1.5) -> +LN -> FFN(mish) -> +LN
// B=8 S=1024 D=512 H=8 hd=64 F=2048.  bf16 MFMA GEMMs, fp32 accum/epilogues.
// Round 20: R7 config (best, 329.9us) + gemm_scores (R9, theory-positive)
// + NEW gemm_pv128: PV was the ONLY GEMM at 1 block/CU (grid 256 = CU count,
// zero TLP). BM 256->128, 4 waves x 32-row strips (acc[2][4]), grid
// (8,1,64)=512 blocks, 24 KiB LDS -> >=2 blocks/CU. R10 lesson: fused
// PV-transform costs more than tau-deferral saves -> entmax_rows in-place.
// ---------------------------------------------------------------------------

typedef float f32x4 __attribute__((ext_vector_type(4)));
typedef float f32x2 __attribute__((ext_vector_type(2)));
typedef __bf16 b8 __attribute__((ext_vector_type(8)));

#define DEV static __device__ __forceinline__

DEV unsigned short f2bf(float f) {
  // gfx950: native cast -> v_cvt_pk_bf16_f32 (RNE); compiler pairs casts.
  return __builtin_bit_cast(unsigned short, (__bf16)f);
}
DEV float bf2f(unsigned short b) { return __uint_as_float(((unsigned)b) << 16); }

DEV float mishf(float x) {
  if (x > 20.f) return x;
  float e = __expf(x);
  float u = 1.f + e;
  u *= u;
  return x * ((u - 1.f) / (u + 1.f));
}

DEV void async16(const void* g, void* l) {
  __builtin_amdgcn_global_load_lds(
      (const __attribute__((address_space(1))) unsigned int*)g,
      (__attribute__((address_space(3))) unsigned int*)l, 16, 0, 0);
}

DEV int mbcnt64(unsigned long long m) {
  return __builtin_amdgcn_mbcnt_hi((unsigned)(m >> 32),
                                   __builtin_amdgcn_mbcnt_lo((unsigned)m, 0));
}

// --- DPP-based wave64 reductions (VALU for xor1..8, LDS only for 16/32) ----
template <int CTRL>
DEV float dppmov(float x) {
  return __builtin_bit_cast(
      float, __builtin_amdgcn_update_dpp(0, __builtin_bit_cast(int, x), CTRL,
                                         0xF, 0xF, true));
}
DEV float swz16(float x) {  // xor-16 within each 32-lane half
  return __builtin_bit_cast(
      float, __builtin_amdgcn_ds_swizzle(__builtin_bit_cast(int, x), 0x401F));
}
DEV float wave_sum(float x) {
  x += dppmov<0xB1>(x);    // quad_perm [1,0,3,2]  (xor 1)
  x += dppmov<0x4E>(x);    // quad_perm [2,3,0,1]  (xor 2)
  x += dppmov<0x141>(x);   // row_half_mirror      (xor 4 pattern)
  x += dppmov<0x140>(x);   // row_mirror           (xor 8 pattern)
  x += swz16(x);
  x += __shfl_xor(x, 32);
  return x;
}
DEV float wave_max(float x) {
  x = fmaxf(x, dppmov<0xB1>(x));
  x = fmaxf(x, dppmov<0x4E>(x));
  x = fmaxf(x, dppmov<0x141>(x));
  x = fmaxf(x, dppmov<0x140>(x));
  x = fmaxf(x, swz16(x));
  x = fmaxf(x, __shfl_xor(x, 32));
  return x;
}

// ---------------------------------------------------------------------------
// Generic MFMA GEMM:  C[M,N] = alpha * A[M,K] * Bt[N,K]^T (+bias) (+mish)
// Batched / split-K via blockIdx.z: off = (z/hdiv)*s1 + (z%hdiv)*s2.
// BK=64: LDS row = 8 groups of 8 bf16; slot s of row m holds group s^(m&7).
// Single-buffer, 2 barriers/K-step (proven optimum for this regime).
// ---------------------------------------------------------------------------
template <int WM, int WN, int EPI, bool OUTBF>
__global__ __launch_bounds__(256) void gemm_bt(
    const unsigned short* __restrict__ A, const unsigned short* __restrict__ Bt,
    const float* __restrict__ bias, void* __restrict__ Cp,
    int K, int lda, int ldb, int ldc,
    long sA1, long sA2, long sB1, long sB2, long sC1, long sC2,
    int hdiv, float alpha) {
  constexpr int BM = WM * 64, BN = WN * 64;
  constexpr int NA = WM * 2, NB = WN * 2;  // staging slots per thread
  __shared__ unsigned short smA[BM * 64];
  __shared__ unsigned short smB[BN * 64];

  const int tid = threadIdx.x;
  const int lane = tid & 63;
  const int z = blockIdx.z;
  const long zi = z / hdiv, zr = z % hdiv;
  const unsigned short* Ab = A + zi * sA1 + zr * sA2 + (long)blockIdx.x * BM * lda;
  const unsigned short* Bb = Bt + zi * sB1 + zr * sB2 + (long)blockIdx.y * BN * ldb;

  int siA[NA];
  const unsigned short* gA[NA];
#pragma unroll
  for (int q = 0; q < NA; ++q) {
    int si = q * 256 + tid;
    int m = si >> 3, s = si & 7, g = s ^ (m & 7);
    siA[q] = si;
    gA[q] = Ab + (long)m * lda + g * 8;
  }
  int siB[NB];
  const unsigned short* gB[NB];
#pragma unroll
  for (int q = 0; q < NB; ++q) {
    int si = q * 256 + tid;
    int m = si >> 3, s = si & 7, g = s ^ (m & 7);
    siB[q] = si;
    gB[q] = Bb + (long)m * ldb + g * 8;
  }

  const int w = tid >> 6;
  const int wr = w / WN, wc = w % WN;
  const int fm = lane & 15, fg = lane >> 4;

  int aOff[4][2], bOff[4][2];
#pragma unroll
  for (int i = 0; i < 4; ++i)
#pragma unroll
    for (int ks = 0; ks < 2; ++ks) {
      int m = wr * 64 + i * 16 + fm;
      aOff[i][ks] = (m * 8 + ((ks * 4 + fg) ^ (fm & 7))) * 8;
      int n = wc * 64 + i * 16 + fm;
      bOff[i][ks] = (n * 8 + ((ks * 4 + fg) ^ (fm & 7))) * 8;
    }

  f32x4 acc[4][4];
#pragma unroll
  for (int i = 0; i < 4; ++i)
#pragma unroll
    for (int j = 0; j < 4; ++j) acc[i][j] = (f32x4){0.f, 0.f, 0.f, 0.f};

  for (int k0 = 0; k0 < K; k0 += 64) {
    __syncthreads();
#pragma unroll
    for (int q = 0; q < NA; ++q) async16(gA[q] + k0, (void*)&smA[siA[q] * 8]);
#pragma unroll
    for (int q = 0; q < NB; ++q) async16(gB[q] + k0, (void*)&smB[siB[q] * 8]);
    __syncthreads();  // implies vmcnt(0): staging complete

#pragma unroll
    for (int ks = 0; ks < 2; ++ks) {
      b8 aF[4], bF[4];
#pragma unroll
      for (int i = 0; i < 4; ++i) aF[i] = *(const b8*)&smA[aOff[i][ks]];
#pragma unroll
      for (int j = 0; j < 4; ++j) bF[j] = *(const b8*)&smB[bOff[j][ks]];
#pragma unroll
      for (int i = 0; i < 4; ++i)
#pragma unroll
        for (int j = 0; j < 4; ++j)
          acc[i][j] = __builtin_amdgcn_mfma_f32_16x16x32_bf16(aF[i], bF[j], acc[i][j], 0, 0, 0);
    }
  }

  const long cbase = zi * sC1 + zr * sC2;
  const int row0 = blockIdx.x * BM + wr * 64 + fg * 4;
  const int col0 = blockIdx.y * BN + wc * 64 + fm;
#pragma unroll
  for (int i = 0; i < 4; ++i) {
#pragma unroll
    for (int j = 0; j < 4; ++j) {
      const int col = col0 + j * 16;
      float bv = (EPI >= 1) ? bias[col] : 0.f;
#pragma unroll
      for (int r = 0; r < 4; ++r) {
        const int row = row0 + i * 16 + r;
        float v = acc[i][j][r] * alpha + bv;
        if (EPI == 2) v = mishf(v);
        const long idx = cbase + (long)row * ldc + col;
        if constexpr (OUTBF)
          ((unsigned short*)Cp)[idx] = f2bf(v);
        else
          ((float*)Cp)[idx] = v;
      }
    }
  }
}

// ---------------------------------------------------------------------------
// Scores standalone: P[z][q][k] = (Q K^T)/16, K=64 baked (single K-step).
// Q direct-to-register; only K staged via async16 (16 KiB LDS). One barrier.
// ---------------------------------------------------------------------------
__global__ __launch_bounds__(256) void gemm_scores(
    const unsigned short* __restrict__ QKV, unsigned short* __restrict__ P) {
  __shared__ unsigned short smB[128 * 64];  // K-rows tile, gemm format

  const int tid = threadIdx.x, lane = tid & 63, w = tid >> 6;
  const int wr = w >> 1, wc = w & 1;
  const int fm = lane & 15, fg = lane >> 4;
  const int z = blockIdx.z, b = z >> 3, h = z & 7;
  const long qrow0 = (long)b * 1024 + blockIdx.x * 128;
  const long krow0 = (long)b * 1024 + blockIdx.y * 128;

#pragma unroll
  for (int q = 0; q < 4; ++q) {
    int si = q * 256 + tid;
    int m = si >> 3, s = si & 7, g = s ^ (m & 7);
    async16(QKV + (krow0 + m) * 1536 + 512 + h * 64 + g * 8, (void*)&smB[si * 8]);
  }

  b8 aQ[4][2];
#pragma unroll
  for (int i = 0; i < 4; ++i) {
    const unsigned short* qp =
        QKV + (qrow0 + wr * 64 + i * 16 + fm) * 1536 + h * 64 + fg * 8;
    aQ[i][0] = *(const b8*)qp;
    aQ[i][1] = *(const b8*)(qp + 32);
  }

  __syncthreads();  // implies vmcnt(0): staging + Q loads complete

  f32x4 acc[4][4];
#pragma unroll
  for (int i = 0; i < 4; ++i)
#pragma unroll
    for (int j = 0; j < 4; ++j) acc[i][j] = (f32x4){0.f, 0.f, 0.f, 0.f};

#pragma unroll
  for (int ks = 0; ks < 2; ++ks) {
    b8 bF[4];
#pragma unroll
    for (int j = 0; j < 4; ++j) {
      int n = wc * 64 + j * 16 + fm;
      bF[j] = *(const b8*)&smB[(n * 8 + ((ks * 4 + fg) ^ (fm & 7))) * 8];
    }
#pragma unroll
    for (int i = 0; i < 4; ++i)
#pragma unroll
      for (int j = 0; j < 4; ++j)
        acc[i][j] = __builtin_amdgcn_mfma_f32_16x16x32_bf16(aQ[i][ks], bF[j], acc[i][j], 0, 0, 0);
  }

  unsigned short* Pb = P + (long)z * 1024 * 1024;
  const int row0 = blockIdx.x * 128 + wr * 64 + fg * 4;
  const int col0 = blockIdx.y * 128 + wc * 64 + fm;
#pragma unroll
  for (int i = 0; i < 4; ++i)
#pragma unroll
    for (int j = 0; j < 4; ++j)
#pragma unroll
      for (int r = 0; r < 4; ++r)
        Pb[(long)(row0 + i * 16 + r) * 1024 + col0 + j * 16] =
            f2bf(acc[i][j][r] * 0.0625f);
}

// ---------------------------------------------------------------------------
// PV standalone: attn = P @ V, BM=128 BN=64 BK=64, K=1024.
// 4 waves x 32-row strips (acc[2][4]); grid (8,1,64) = 512 blocks (2+/CU,
// vs old BM=256's 256 blocks = 1/CU with zero TLP). 24 KiB LDS. Same
// staging format / fragment offsets / 2-barrier sbuf loop as gemm_bt.
// ---------------------------------------------------------------------------
__global__ __launch_bounds__(256) void gemm_pv128(
    const unsigned short* __restrict__ P, const unsigned short* __restrict__ Vt,
    unsigned short* __restrict__ attn) {
  __shared__ unsigned short smA[128 * 64];  // 16 KiB
  __shared__ unsigned short smB[64 * 64];   // 8 KiB

  const int tid = threadIdx.x, lane = tid & 63, w = tid >> 6;
  const int fm = lane & 15, fg = lane >> 4;
  const int z = blockIdx.z;
  const long SS = 1024L * 1024L;
  const unsigned short* Ab = P + (long)z * SS + (long)blockIdx.x * 128 * 1024;
  const unsigned short* Bb = Vt + (long)z * 64 * 1024;

  int siA[4];
  const unsigned short* gA[4];
#pragma unroll
  for (int q = 0; q < 4; ++q) {
    int si = q * 256 + tid;
    int m = si >> 3, s = si & 7, g = s ^ (m & 7);
    siA[q] = si;
    gA[q] = Ab + (long)m * 1024 + g * 8;
  }
  int siB[2];
  const unsigned short* gB[2];
#pragma unroll
  for (int q = 0; q < 2; ++q) {
    int si = q * 256 + tid;
    int m = si >> 3, s = si & 7, g = s ^ (m & 7);
    siB[q] = si;
    gB[q] = Bb + (long)m * 1024 + g * 8;
  }

  // wave w owns rows [w*32, w*32+32): fragment rows m = w*32 + i*16 + fm
  // (w*32 and i*16 are 0 mod 8 -> m&7 == fm&7, staging invariant holds)
  int aOff[2][2], bOff[4][2];
#pragma unroll
  for (int ks = 0; ks < 2; ++ks) {
#pragma unroll
    for (int i = 0; i < 2; ++i) {
      int m = w * 32 + i * 16 + fm;
      aOff[i][ks] = (m * 8 + ((ks * 4 + fg) ^ (fm & 7))) * 8;
    }
#pragma unroll
    for (int j = 0; j < 4; ++j) {
      int n = j * 16 + fm;  // all waves share full BN=64
      bOff[j][ks] = (n * 8 + ((ks * 4 + fg) ^ (fm & 7))) * 8;
    }
  }

  f32x4 acc[2][4];
#pragma unroll
  for (int i = 0; i < 2; ++i)
#pragma unroll
    for (int j = 0; j < 4; ++j) acc[i][j] = (f32x4){0.f, 0.f, 0.f, 0.f};

  for (int k0 = 0; k0 < 1024; k0 += 64) {
    __syncthreads();
#pragma unroll
    for (int q = 0; q < 4; ++q) async16(gA[q] + k0, (void*)&smA[siA[q] * 8]);
#pragma unroll
    for (int q = 0; q < 2; ++q) async16(gB[q] + k0, (void*)&smB[siB[q] * 8]);
    __syncthreads();  // implies vmcnt(0): staging complete

#pragma unroll
    for (int ks = 0; ks < 2; ++ks) {
      b8 aF[2], bF[4];
#pragma unroll
      for (int i = 0; i < 2; ++i) aF[i] = *(const b8*)&smA[aOff[i][ks]];
#pragma unroll
      for (int j = 0; j < 4; ++j) bF[j] = *(const b8*)&smB[bOff[j][ks]];
#pragma unroll
      for (int i = 0; i < 2; ++i)
#pragma unroll
        for (int j = 0; j < 4; ++j)
          acc[i][j] = __builtin_amdgcn_mfma_f32_16x16x32_bf16(aF[i], bF[j], acc[i][j], 0, 0, 0);
    }
  }

  const long cbase = (long)(z >> 3) * 1024 * 512 + (z & 7) * 64;
  const int row0 = blockIdx.x * 128 + w * 32 + fg * 4;
#pragma unroll
  for (int i = 0; i < 2; ++i)
#pragma unroll
    for (int j = 0; j < 4; ++j) {
      const int col = fm + j * 16;
#pragma unroll
      for (int r = 0; r < 4; ++r) {
        const int row = row0 + i * 16 + r;
        attn[cbase + (long)row * 512 + col] = f2bf(acc[i][j][r]);
      }
    }
}

// ---------------------------------------------------------------------------
// FFN1 standalone: hb = mish(x1b @ W1t^T + b1), dbuf, 1 barrier/K-step.
// ---------------------------------------------------------------------------
__global__ __launch_bounds__(256) void gemm_ffn1(
    const unsigned short* __restrict__ A, const unsigned short* __restrict__ Bt,
    const float* __restrict__ bias, unsigned short* __restrict__ C) {
  __shared__ unsigned short smA[2 * 128 * 64];
  __shared__ unsigned short smB[2 * 128 * 64];

  const int tid = threadIdx.x;
  const int lane = tid & 63;
  const unsigned short* Ab = A + (long)blockIdx.x * 128 * 512;
  const unsigned short* Bb = Bt + (long)blockIdx.y * 128 * 512;

  int siA[4], siB[4];
  const unsigned short* gA[4];
  const unsigned short* gB[4];
#pragma unroll
  for (int q = 0; q < 4; ++q) {
    int si = q * 256 + tid;
    int m = si >> 3, s = si & 7, g = s ^ (m & 7);
    siA[q] = si;
    siB[q] = si;
    gA[q] = Ab + (long)m * 512 + g * 8;
    gB[q] = Bb + (long)m * 512 + g * 8;
  }

  const int w = tid >> 6;
  const int wr = w >> 1, wc = w & 1;
  const int fm = lane & 15, fg = lane >> 4;

  int aOff[4][2], bOff[4][2];
#pragma unroll
  for (int i = 0; i < 4; ++i)
#pragma unroll
    for (int ks = 0; ks < 2; ++ks) {
      int m = wr * 64 + i * 16 + fm;
      aOff[i][ks] = (m * 8 + ((ks * 4 + fg) ^ (fm & 7))) * 8;
      int n = wc * 64 + i * 16 + fm;
      bOff[i][ks] = (n * 8 + ((ks * 4 + fg) ^ (fm & 7))) * 8;
    }

  f32x4 acc[4][4];
#pragma unroll
  for (int i = 0; i < 4; ++i)
#pragma unroll
    for (int j = 0; j < 4; ++j) acc[i][j] = (f32x4){0.f, 0.f, 0.f, 0.f};

  auto stage = [&](int buf, int k0) {
    unsigned short* dA = smA + buf * (128 * 64);
    unsigned short* dB = smB + buf * (128 * 64);
#pragma unroll
    for (int q = 0; q < 4; ++q) async16(gA[q] + k0, (void*)&dA[siA[q] * 8]);
#pragma unroll
    for (int q = 0; q < 4; ++q) async16(gB[q] + k0, (void*)&dB[siB[q] * 8]);
  };
  auto compute = [&](int buf) {
    const unsigned short* sA = smA + buf * (128 * 64);
    const unsigned short* sB = smB + buf * (128 * 64);
#pragma unroll
    for (int ks = 0; ks < 2; ++ks) {
      b8 aF[4], bF[4];
#pragma unroll
      for (int i = 0; i < 4; ++i) aF[i] = *(const b8*)&sA[aOff[i][ks]];
#pragma unroll
      for (int j = 0; j < 4; ++j) bF[j] = *(const b8*)&sB[bOff[j][ks]];
#pragma unroll
      for (int i = 0; i < 4; ++i)
#pragma unroll
        for (int j = 0; j < 4; ++j)
          acc[i][j] = __builtin_amdgcn_mfma_f32_16x16x32_bf16(aF[i], bF[j], acc[i][j], 0, 0, 0);
    }
  };

  stage(0, 0);
  __syncthreads();
  int cur = 0;
  for (int k0 = 64; k0 < 512; k0 += 64) {
    stage(cur ^ 1, k0);
    compute(cur);
    __syncthreads();
    cur ^= 1;
  }
  compute(cur);

  const int row0 = blockIdx.x * 128 + wr * 64 + fg * 4;
  const int col0 = blockIdx.y * 128 + wc * 64 + fm;
#pragma unroll
  for (int i = 0; i < 4; ++i) {
#pragma unroll
    for (int j = 0; j < 4; ++j) {
      const int col = col0 + j * 16;
      const float bv = bias[col];
#pragma unroll
      for (int r = 0; r < 4; ++r) {
        const int row = row0 + i * 16 + r;
        C[(long)row * 2048 + col] = f2bf(mishf(acc[i][j][r] + bv));
      }
    }
  }
}

// ---------------------------------------------------------------------------
// entmax 1.5 over rows of 1024 (in-place bf16). One wave per row.
// Candidate compaction (only z > m-1 can ever be in support), register fast
// paths for <=128 / <=256 candidates, LDS loop fallback. DPP reductions.
// ---------------------------------------------------------------------------
template <int NC>
DEV float solve_tau(const f32x2* zc, float tau) {
  int kprev = -1;
  const f32x2 zero2 = (f32x2){0.f, 0.f};
  for (int it = 0; it < 12; ++it) {
    const f32x2 t2 = (f32x2){tau, tau};
    f32x2 s1v = zero2, s2v = zero2;
    int k = 0;
#pragma unroll
    for (int i = 0; i < NC; ++i) {
      f32x2 h = zc[i] - t2;
      k += __popcll(__ballot(h.x > 0.f));
      k += __popcll(__ballot(h.y > 0.f));
      f32x2 hp = __builtin_elementwise_max(h, zero2);
      s1v += hp;
      s2v += hp * hp;
    }
    float s1 = wave_sum(s1v.x + s1v.y);
    float s2 = wave_sum(s2v.x + s2v.y);
    if (k == kprev) break;  // support fixed point -> tau exact (wave-uniform)
    kprev = k;
    float kf = (float)k;
    float disc = fmaxf(fmaf(s1, s1, -kf * (s2 - 1.f)), 0.f);
    tau += (s1 - __builtin_sqrtf(disc)) / kf;
  }
  return tau;
}

DEV float solve_tau_lds(const float* cw, int nch, int lane, float tau) {
  int kprev = -1;
  const f32x2 zero2 = (f32x2){0.f, 0.f};
  for (int it = 0; it < 12; ++it) {
    const f32x2 t2 = (f32x2){tau, tau};
    f32x2 s1v = zero2, s2v = zero2;
    int k = 0;
    for (int c = 0; c < nch; ++c) {
      f32x2 h = *(const f32x2*)&cw[c * 128 + lane * 2] - t2;
      k += __popcll(__ballot(h.x > 0.f));
      k += __popcll(__ballot(h.y > 0.f));
      f32x2 hp = __builtin_elementwise_max(h, zero2);
      s1v += hp;
      s2v += hp * hp;
    }
    float s1 = wave_sum(s1v.x + s1v.y);
    float s2 = wave_sum(s2v.x + s2v.y);
    if (k == kprev) break;
    kprev = k;
    float kf = (float)k;
    float disc = fmaxf(fmaf(s1, s1, -kf * (s2 - 1.f)), 0.f);
    tau += (s1 - __builtin_sqrtf(disc)) / kf;
  }
  return tau;
}

__global__ __launch_bounds__(256) void entmax_rows(unsigned short* __restrict__ P) {
  const int tid = threadIdx.x, lane = tid & 63, wv = tid >> 6;
  const long row = (long)blockIdx.x * 4 + wv;
  unsigned short* p = P + row * 1024;
  __shared__ float cand[4][1024];  // per-wave candidate buffer (16 KiB)

  union { uint4 v; unsigned short u[8]; } a, b;
  a.v = *(const uint4*)(p + lane * 16);
  b.v = *(const uint4*)(p + lane * 16 + 8);
  f32x2 zp[8];
#pragma unroll
  for (int i = 0; i < 4; ++i) {
    zp[i] = (f32x2){bf2f(a.u[2 * i]), bf2f(a.u[2 * i + 1])};
    zp[4 + i] = (f32x2){bf2f(b.u[2 * i]), bf2f(b.u[2 * i + 1])};
  }

  f32x2 mv = zp[0];
#pragma unroll
  for (int i = 1; i < 8; ++i) mv = __builtin_elementwise_max(mv, zp[i]);
  float m = wave_max(fmaxf(mv.x, mv.y));

  const float thr = m - 1.f;
  float* cw = cand[wv];

  // compact candidates (z > thr) into cw[0..base)
  int base = 0;
#pragma unroll
  for (int i = 0; i < 8; ++i) {
    unsigned long long mx = __ballot(zp[i].x > thr);
    if (zp[i].x > thr) cw[base + mbcnt64(mx)] = zp[i].x;
    base += __popcll(mx);
    unsigned long long my = __ballot(zp[i].y > thr);
    if (zp[i].y > thr) cw[base + mbcnt64(my)] = zp[i].y;
    base += __popcll(my);
  }

  // pad to a multiple of 128 with a value that never contributes
  const int nch = (base + 127) >> 7;  // 1..8 chunks of 128
  for (int i = base + lane; i < nch * 128; i += 64) cw[i] = -1e30f;

  float tau;
  if (nch == 1) {
    f32x2 zc[1];
    zc[0] = *(const f32x2*)&cw[lane * 2];
    tau = solve_tau<1>(zc, thr);
  } else if (nch == 2) {
    f32x2 zc[2];
    zc[0] = *(const f32x2*)&cw[lane * 2];
    zc[1] = *(const f32x2*)&cw[128 + lane * 2];
    tau = solve_tau<2>(zc, thr);
  } else {
    tau = solve_tau_lds(cw, nch, lane, thr);
  }

  const f32x2 t2 = (f32x2){tau, tau};
  const f32x2 zero2 = (f32x2){0.f, 0.f};
#pragma unroll
  for (int i = 0; i < 4; ++i) {
    f32x2 h0 = __builtin_elementwise_max(zp[i] - t2, zero2);
    f32x2 h1 = __builtin_elementwise_max(zp[4 + i] - t2, zero2);
    f32x2 p0 = h0 * h0, p1 = h1 * h1;
    a.u[2 * i] = f2bf(p0.x);
    a.u[2 * i + 1] = f2bf(p0.y);
    b.u[2 * i] = f2bf(p1.x);
    b.u[2 * i + 1] = f2bf(p1.y);
  }
  *(uint4*)(p + lane * 16) = a.v;
  *(uint4*)(p + lane * 16 + 8) = b.v;
}

// ---------------------------------------------------------------------------
// Merged prep: x cast + 6 weight transposes + bias concat in ONE launch.
// ---------------------------------------------------------------------------
__global__ __launch_bounds__(256) void prep_all(
    const float* __restrict__ x, unsigned short* __restrict__ xb,
    const float* __restrict__ Wq, const float* __restrict__ Wk,
    const float* __restrict__ Wv, const float* __restrict__ Wo,
    const float* __restrict__ W1, const float* __restrict__ W2,
    unsigned short* __restrict__ Wqkvt, unsigned short* __restrict__ Wot,
    unsigned short* __restrict__ W1t, unsigned short* __restrict__ W2t,
    const float* __restrict__ bq, const float* __restrict__ bk,
    const float* __restrict__ bv, float* __restrict__ bqkv) {
  __shared__ float t[32][33];
  const int bid = blockIdx.x, tid = threadIdx.x;

  if (bid < 4096) {  // cast x -> bf16, 4 elems/thread
    long i = ((long)bid * 256 + tid) * 4;
    float4 v = *(const float4*)&x[i];
    uint2 pk;
    pk.x = (unsigned)f2bf(v.x) | ((unsigned)f2bf(v.y) << 16);
    pk.y = (unsigned)f2bf(v.z) | ((unsigned)f2bf(v.w) << 16);
    *(uint2*)&xb[i] = pk;
    return;
  }

  const float* in;
  unsigned short* out;
  int ldi, ldo, bx, by;
  if (bid < 5120) {
    int t4 = (bid - 4096) >> 8, local = (bid - 4096) & 255;
    const float* ins[4] = {Wq, Wk, Wv, Wo};
    unsigned short* outs[4] = {Wqkvt, Wqkvt + 512 * 512, Wqkvt + 2 * 512 * 512, Wot};
    in = ins[t4];
    out = outs[t4];
    ldi = 512;
    ldo = 512;
    bx = local & 15;
    by = local >> 4;
  } else if (bid < 6144) {
    int local = bid - 5120;  // W1 [512][2048] -> W1t [2048][512]
    in = W1;
    out = W1t;
    ldi = 2048;
    ldo = 512;
    bx = local & 63;
    by = local >> 6;
  } else if (bid < 7168) {
    int local = bid - 6144;  // W2 [2048][512] -> W2t [512][2048]
    in = W2;
    out = W2t;
    ldi = 512;
    ldo = 2048;
    bx = local & 15;
    by = local >> 4;
  } else {  // concat biases
    int i = (bid - 7168) * 256 + tid;
    if (i < 512) bqkv[i] = bq[i];
    else if (i < 1024) bqkv[i] = bk[i - 512];
    else if (i < 1536) bqkv[i] = bv[i - 1024];
    return;
  }

  const int tx = tid & 31, ty = tid >> 5;
  const int r0 = by * 32, c0 = bx * 32;
#pragma unroll
  for (int q = 0; q < 4; ++q) {
    int r = ty + q * 8;
    t[r][tx] = in[(long)(r0 + r) * ldi + c0 + tx];
  }
  __syncthreads();
#pragma unroll
  for (int q = 0; q < 4; ++q) {
    int r = ty + q * 8;
    out[(long)(c0 + r) * ldo + r0 + tx] = f2bf(t[tx][r]);
  }
}

// bf16 batched transpose (for V -> V^T per (b,h))
__global__ __launch_bounds__(256) void transpose_b2b(const unsigned short* __restrict__ in,
                                                     unsigned short* __restrict__ out,
                                                     int ldi, int ldo, long i1, long i2,
                                                     long o1, long o2, int hdiv) {
  __shared__ unsigned short t[32][33];
  const int z = blockIdx.z;
  in += (long)(z / hdiv) * i1 + (long)(z % hdiv) * i2;
  out += (long)(z / hdiv) * o1 + (long)(z % hdiv) * o2;
  const int tx = threadIdx.x & 31, ty = threadIdx.x >> 5;
  const int r0 = blockIdx.y * 32, c0 = blockIdx.x * 32;
#pragma unroll
  for (int q = 0; q < 4; ++q) {
    int r = ty + q * 8;
    t[r][tx] = in[(long)(r0 + r) * ldi + c0 + tx];
  }
  __syncthreads();
#pragma unroll
  for (int q = 0; q < 4; ++q) {
    int r = ty + q * 8;
    out[(long)(c0 + r) * ldo + r0 + tx] = t[tx][r];
  }
}

// ---------------------------------------------------------------------------
// out = xin + LayerNorm(sum_j y[j*ystr] + ybias)*g + be   (row 512)
// ---------------------------------------------------------------------------
template <bool WB, int NS>
__global__ __launch_bounds__(256) void ln_res(const float* __restrict__ xin,
                                              const float* __restrict__ y, long ystr,
                                              const float* __restrict__ ybias,
                                              const float* __restrict__ g,
                                              const float* __restrict__ be,
                                              float* __restrict__ xo,
                                              unsigned short* __restrict__ xob) {
  const int row = blockIdx.x, tid = threadIdx.x, lane = tid & 63, wv = tid >> 6;
  const long base = (long)row * 512 + tid * 2;
  const int c = tid * 2;
  float2 v = *(const float2*)&y[base];
#pragma unroll
  for (int j = 1; j < NS; ++j) {
    float2 u = *(const float2*)&y[base + j * ystr];
    v.x += u.x;
    v.y += u.y;
  }
  v.x += ybias[c];
  v.y += ybias[c + 1];
  float s1 = wave_sum(v.x + v.y);
  float s2 = wave_sum(v.x * v.x + v.y * v.y);
  __shared__ float red[4][2];
  if (lane == 0) {
    red[wv][0] = s1;
    red[wv][1] = s2;
  }
  __syncthreads();
  s1 = red[0][0] + red[1][0] + red[2][0] + red[3][0];
  s2 = red[0][1] + red[1][1] + red[2][1] + red[3][1];
  const float mu = s1 * (1.f / 512.f);
  const float rstd = rsqrtf(s2 * (1.f / 512.f) - mu * mu + 1e-5f);
  float2 xv = *(const float2*)&xin[base];
  float o0 = xv.x + (v.x - mu) * rstd * g[c] + be[c];
  float o1 = xv.y + (v.y - mu) * rstd * g[c + 1] + be[c + 1];
  float2 ov;
  ov.x = o0;
  ov.y = o1;
  *(float2*)&xo[base] = ov;
  if constexpr (WB) {
    unsigned pk = (unsigned)f2bf(o0) | ((unsigned)f2bf(o1) << 16);
    *(unsigned*)&xob[base] = pk;
  }
}

// ---------------------------------------------------------------------------
extern "C" void kernel_launch(void* const* d_in, const int* in_sizes, int n_in,
                              void* d_out, int out_size, void* d_ws, size_t ws_size,
                              hipStream_t stream) {
  const int B = 8, S = 1024, D = 512, H = 8, F = 2048;
  const int BS = B * S;  // 8192 rows
  const int N3 = 3 * D;  // 1536

  const float* x = (const float*)d_in[0];
  const float* Wq = (const float*)d_in[1];
  const float* bq = (const float*)d_in[2];
  const float* Wk = (const float*)d_in[3];
  const float* bk = (const float*)d_in[4];
  const float* Wv = (const float*)d_in[5];
  const float* bv = (const float*)d_in[6];
  const float* Wo = (const float*)d_in[7];
  const float* bo = (const float*)d_in[8];
  const float* g1 = (const float*)d_in[9];
  const float* be1 = (const float*)d_in[10];
  const float* W1 = (const float*)d_in[11];
  const float* b1 = (const float*)d_in[12];
  const float* W2 = (const float*)d_in[13];
  const float* b2 = (const float*)d_in[14];
  const float* g2 = (const float*)d_in[15];
  const float* be2 = (const float*)d_in[16];
  float* out = (float*)d_out;

  char* w = (char*)d_ws;
  size_t off = 0;
  auto alloc = [&](size_t bytes) -> void* {
    void* p = w + off;
    off += bytes;
    off = (off + 255) & ~(size_t)255;
    return p;
  };

  unsigned short* xb = (unsigned short*)alloc((size_t)BS * D * 2);
  unsigned short* Wqkvt = (unsigned short*)alloc((size_t)N3 * D * 2);
  unsigned short* Wot = (unsigned short*)alloc((size_t)D * D * 2);
  unsigned short* W1t = (unsigned short*)alloc((size_t)F * D * 2);
  unsigned short* W2t = (unsigned short*)alloc((size_t)D * F * 2);
  float* bqkv = (float*)alloc((size_t)N3 * 4);
  unsigned short* QKVb = (unsigned short*)alloc((size_t)BS * N3 * 2);
  unsigned short* Vt = (unsigned short*)alloc((size_t)BS * D * 2);
  unsigned short* attn = (unsigned short*)alloc((size_t)BS * D * 2);
  unsigned short* P = (unsigned short*)alloc((size_t)B * H * S * S * 2);  // 128 MiB
  float* x1 = (float*)alloc((size_t)BS * D * 4);
  unsigned short* hb = (unsigned short*)alloc((size_t)BS * F * 2);
  unsigned short* x1b = xb;   // reuse: xb dead after QKV GEMM
  float* yp = (float*)P;      // reuse: P dead after PV GEMM
  const long PSTR = (long)BS * D;

  // 1) merged prep: cast x, transpose all weights, concat qkv bias
  prep_all<<<7174, 256, 0, stream>>>(x, xb, Wq, Wk, Wv, Wo, W1, W2,
                                     Wqkvt, Wot, W1t, W2t, bq, bk, bv, bqkv);

  // 2) merged QKV projection: [8192][1536] bf16
  gemm_bt<2, 2, 1, true><<<dim3(BS / 128, N3 / 128, 1), 256, 0, stream>>>(
      xb, Wqkvt, bqkv, QKVb, D, D, D, N3, 0, 0, 0, 0, 0, 0, 1, 1.f);

  // 3) V -> Vt[(b,h), d, s]
  transpose_b2b<<<dim3(2, 32, 64), 256, 0, stream>>>(
      QKVb + 1024, Vt, N3, S, (long)S * N3, 64, (long)8 * 64 * S, (long)64 * S, 8);

  // 4) scores z = (Q K^T)/16 -> P bf16 (standalone, K=64 baked, Q-in-reg)
  gemm_scores<<<dim3(S / 128, S / 128, B * H), 256, 0, stream>>>(QKVb, P);

  // 5) entmax-1.5 per row, in place (candidate-compacted support iteration)
  entmax_rows<<<(B * H * S) / 4, 256, 0, stream>>>(P);

  // 6) attn = P @ V  (BM=128: 512 blocks, 2+/CU - PV was the only 1/CU GEMM)
  gemm_pv128<<<dim3(S / 128, 1, B * H), 256, 0, stream>>>(P, Vt, attn);

  // 7) y = attn @ Wo, split-K x2 (bias folded into ln_res)
  gemm_bt<2, 2, 0, false><<<dim3(BS / 128, D / 128, 2), 256, 0, stream>>>(
      attn, Wot, nullptr, yp, D / 2, D, D, D, 0, D / 2, 0, D / 2, 0, PSTR, 2, 1.f);

  // 8) x1 = x + LN(y0+y1+bo)*g1 + be1
  ln_res<true, 2><<<BS, 256, 0, stream>>>(x, yp, PSTR, bo, g1, be1, x1, x1b);

  // 9) h = mish(x1 @ W1 + b1) (bf16) - standalone dbuf kernel
  gemm_ffn1<<<dim3(BS / 128, F / 128, 1), 256, 0, stream>>>(x1b, W1t, b1, hb);

  // 10) y2 = h @ W2, split-K x2 (K-chunks of 1024)
  gemm_bt<2, 2, 0, false><<<dim3(BS / 128, D / 128, 2), 256, 0, stream>>>(
      hb, W2t, nullptr, yp, F / 2, F, F, D, 0, F / 2, 0, F / 2, 0, PSTR, 2, 1.f);

  // 11) out = x1 + LN(y0+y1+b2)*g2 + be2
  ln_res<false, 2><<<BS, 256, 0, stream>>>(x1, yp, PSTR, b2, g2, be2, out, nullptr);
}

// Round 12
// 329.354 us; speedup vs baseline: 1.0395x; 1.0236x over previous
//
#include <hip/hip_runtime.h>

// ---------------------------------------------------------------------------
// EncoderLayer: x -> MHA(entmax1.5) -> +LN -> FFN(mish) -> +LN
// B=8 S=1024 D=512 H=8 hd=64 F=2048.  bf16 MFMA GEMMs, fp32 accum/epilogues.
// FINAL (R7 config, best measured 329.9us): all sbuf gemm_bt (2-barrier
// K-loop: 4x evidence that block-TLP beats LDS-costing pipelining at these
// shapes), standalone dbuf gemm_ffn1, in-place entmax_rows with candidate
// compaction (z > m-1 only) + DPP wave reductions. R8-R11 tested counted-
// vmcnt, Q-in-reg scores, tau-deferral, PV-occupancy: all within or below
// noise (+-2% total; identical GEMM code swings +-17% across rounds).
// ---------------------------------------------------------------------------

typedef float f32x4 __attribute__((ext_vector_type(4)));
typedef float f32x2 __attribute__((ext_vector_type(2)));
typedef __bf16 b8 __attribute__((ext_vector_type(8)));

#define DEV static __device__ __forceinline__

DEV unsigned short f2bf(float f) {
  // gfx950: native cast -> v_cvt_pk_bf16_f32 (RNE); compiler pairs casts.
  return __builtin_bit_cast(unsigned short, (__bf16)f);
}
DEV float bf2f(unsigned short b) { return __uint_as_float(((unsigned)b) << 16); }

DEV float mishf(float x) {
  if (x > 20.f) return x;
  float e = __expf(x);
  float u = 1.f + e;
  u *= u;
  return x * ((u - 1.f) / (u + 1.f));
}

DEV void async16(const void* g, void* l) {
  __builtin_amdgcn_global_load_lds(
      (const __attribute__((address_space(1))) unsigned int*)g,
      (__attribute__((address_space(3))) unsigned int*)l, 16, 0, 0);
}

DEV int mbcnt64(unsigned long long m) {
  return __builtin_amdgcn_mbcnt_hi((unsigned)(m >> 32),
                                   __builtin_amdgcn_mbcnt_lo((unsigned)m, 0));
}

// --- DPP-based wave64 reductions (VALU for xor1..8, LDS only for 16/32) ----
template <int CTRL>
DEV float dppmov(float x) {
  return __builtin_bit_cast(
      float, __builtin_amdgcn_update_dpp(0, __builtin_bit_cast(int, x), CTRL,
                                         0xF, 0xF, true));
}
DEV float swz16(float x) {  // xor-16 within each 32-lane half
  return __builtin_bit_cast(
      float, __builtin_amdgcn_ds_swizzle(__builtin_bit_cast(int, x), 0x401F));
}
DEV float wave_sum(float x) {
  x += dppmov<0xB1>(x);    // quad_perm [1,0,3,2]  (xor 1)
  x += dppmov<0x4E>(x);    // quad_perm [2,3,0,1]  (xor 2)
  x += dppmov<0x141>(x);   // row_half_mirror      (xor 4 pattern)
  x += dppmov<0x140>(x);   // row_mirror           (xor 8 pattern)
  x += swz16(x);
  x += __shfl_xor(x, 32);
  return x;
}
DEV float wave_max(float x) {
  x = fmaxf(x, dppmov<0xB1>(x));
  x = fmaxf(x, dppmov<0x4E>(x));
  x = fmaxf(x, dppmov<0x141>(x));
  x = fmaxf(x, dppmov<0x140>(x));
  x = fmaxf(x, swz16(x));
  x = fmaxf(x, __shfl_xor(x, 32));
  return x;
}

// ---------------------------------------------------------------------------
// Generic MFMA GEMM:  C[M,N] = alpha * A[M,K] * Bt[N,K]^T (+bias) (+mish)
// Batched / split-K via blockIdx.z: off = (z/hdiv)*s1 + (z%hdiv)*s2.
// BK=64: LDS row = 8 groups of 8 bf16; slot s of row m holds group s^(m&7).
// Single-buffer, 2 barriers/K-step (proven optimum for this regime).
// ---------------------------------------------------------------------------
template <int WM, int WN, int EPI, bool OUTBF>
__global__ __launch_bounds__(256) void gemm_bt(
    const unsigned short* __restrict__ A, const unsigned short* __restrict__ Bt,
    const float* __restrict__ bias, void* __restrict__ Cp,
    int K, int lda, int ldb, int ldc,
    long sA1, long sA2, long sB1, long sB2, long sC1, long sC2,
    int hdiv, float alpha) {
  constexpr int BM = WM * 64, BN = WN * 64;
  constexpr int NA = WM * 2, NB = WN * 2;  // staging slots per thread
  __shared__ unsigned short smA[BM * 64];
  __shared__ unsigned short smB[BN * 64];

  const int tid = threadIdx.x;
  const int lane = tid & 63;
  const int z = blockIdx.z;
  const long zi = z / hdiv, zr = z % hdiv;
  const unsigned short* Ab = A + zi * sA1 + zr * sA2 + (long)blockIdx.x * BM * lda;
  const unsigned short* Bb = Bt + zi * sB1 + zr * sB2 + (long)blockIdx.y * BN * ldb;

  int siA[NA];
  const unsigned short* gA[NA];
#pragma unroll
  for (int q = 0; q < NA; ++q) {
    int si = q * 256 + tid;
    int m = si >> 3, s = si & 7, g = s ^ (m & 7);
    siA[q] = si;
    gA[q] = Ab + (long)m * lda + g * 8;
  }
  int siB[NB];
  const unsigned short* gB[NB];
#pragma unroll
  for (int q = 0; q < NB; ++q) {
    int si = q * 256 + tid;
    int m = si >> 3, s = si & 7, g = s ^ (m & 7);
    siB[q] = si;
    gB[q] = Bb + (long)m * ldb + g * 8;
  }

  const int w = tid >> 6;
  const int wr = w / WN, wc = w % WN;
  const int fm = lane & 15, fg = lane >> 4;

  int aOff[4][2], bOff[4][2];
#pragma unroll
  for (int i = 0; i < 4; ++i)
#pragma unroll
    for (int ks = 0; ks < 2; ++ks) {
      int m = wr * 64 + i * 16 + fm;
      aOff[i][ks] = (m * 8 + ((ks * 4 + fg) ^ (fm & 7))) * 8;
      int n = wc * 64 + i * 16 + fm;
      bOff[i][ks] = (n * 8 + ((ks * 4 + fg) ^ (fm & 7))) * 8;
    }

  f32x4 acc[4][4];
#pragma unroll
  for (int i = 0; i < 4; ++i)
#pragma unroll
    for (int j = 0; j < 4; ++j) acc[i][j] = (f32x4){0.f, 0.f, 0.f, 0.f};

  for (int k0 = 0; k0 < K; k0 += 64) {
    __syncthreads();
#pragma unroll
    for (int q = 0; q < NA; ++q) async16(gA[q] + k0, (void*)&smA[siA[q] * 8]);
#pragma unroll
    for (int q = 0; q < NB; ++q) async16(gB[q] + k0, (void*)&smB[siB[q] * 8]);
    __syncthreads();  // implies vmcnt(0): staging complete

#pragma unroll
    for (int ks = 0; ks < 2; ++ks) {
      b8 aF[4], bF[4];
#pragma unroll
      for (int i = 0; i < 4; ++i) aF[i] = *(const b8*)&smA[aOff[i][ks]];
#pragma unroll
      for (int j = 0; j < 4; ++j) bF[j] = *(const b8*)&smB[bOff[j][ks]];
#pragma unroll
      for (int i = 0; i < 4; ++i)
#pragma unroll
        for (int j = 0; j < 4; ++j)
          acc[i][j] = __builtin_amdgcn_mfma_f32_16x16x32_bf16(aF[i], bF[j], acc[i][j], 0, 0, 0);
    }
  }

  const long cbase = zi * sC1 + zr * sC2;
  const int row0 = blockIdx.x * BM + wr * 64 + fg * 4;
  const int col0 = blockIdx.y * BN + wc * 64 + fm;
#pragma unroll
  for (int i = 0; i < 4; ++i) {
#pragma unroll
    for (int j = 0; j < 4; ++j) {
      const int col = col0 + j * 16;
      float bv = (EPI >= 1) ? bias[col] : 0.f;
#pragma unroll
      for (int r = 0; r < 4; ++r) {
        const int row = row0 + i * 16 + r;
        float v = acc[i][j][r] * alpha + bv;
        if (EPI == 2) v = mishf(v);
        const long idx = cbase + (long)row * ldc + col;
        if constexpr (OUTBF)
          ((unsigned short*)Cp)[idx] = f2bf(v);
        else
          ((float*)Cp)[idx] = v;
      }
    }
  }
}

// ---------------------------------------------------------------------------
// FFN1 standalone: hb = mish(x1b @ W1t^T + b1), [8192x2048] K=512, bf16 out.
// Double-buffered staging, 1 barrier/K-step. Separate function so template
// codegen coupling (rule #19) can't perturb it. BM=BN=128.
// ---------------------------------------------------------------------------
__global__ __launch_bounds__(256) void gemm_ffn1(
    const unsigned short* __restrict__ A, const unsigned short* __restrict__ Bt,
    const float* __restrict__ bias, unsigned short* __restrict__ C) {
  __shared__ unsigned short smA[2 * 128 * 64];
  __shared__ unsigned short smB[2 * 128 * 64];

  const int tid = threadIdx.x;
  const int lane = tid & 63;
  const unsigned short* Ab = A + (long)blockIdx.x * 128 * 512;
  const unsigned short* Bb = Bt + (long)blockIdx.y * 128 * 512;

  int siA[4], siB[4];
  const unsigned short* gA[4];
  const unsigned short* gB[4];
#pragma unroll
  for (int q = 0; q < 4; ++q) {
    int si = q * 256 + tid;
    int m = si >> 3, s = si & 7, g = s ^ (m & 7);
    siA[q] = si;
    siB[q] = si;
    gA[q] = Ab + (long)m * 512 + g * 8;
    gB[q] = Bb + (long)m * 512 + g * 8;
  }

  const int w = tid >> 6;
  const int wr = w >> 1, wc = w & 1;
  const int fm = lane & 15, fg = lane >> 4;

  int aOff[4][2], bOff[4][2];
#pragma unroll
  for (int i = 0; i < 4; ++i)
#pragma unroll
    for (int ks = 0; ks < 2; ++ks) {
      int m = wr * 64 + i * 16 + fm;
      aOff[i][ks] = (m * 8 + ((ks * 4 + fg) ^ (fm & 7))) * 8;
      int n = wc * 64 + i * 16 + fm;
      bOff[i][ks] = (n * 8 + ((ks * 4 + fg) ^ (fm & 7))) * 8;
    }

  f32x4 acc[4][4];
#pragma unroll
  for (int i = 0; i < 4; ++i)
#pragma unroll
    for (int j = 0; j < 4; ++j) acc[i][j] = (f32x4){0.f, 0.f, 0.f, 0.f};

  auto stage = [&](int buf, int k0) {
    unsigned short* dA = smA + buf * (128 * 64);
    unsigned short* dB = smB + buf * (128 * 64);
#pragma unroll
    for (int q = 0; q < 4; ++q) async16(gA[q] + k0, (void*)&dA[siA[q] * 8]);
#pragma unroll
    for (int q = 0; q < 4; ++q) async16(gB[q] + k0, (void*)&dB[siB[q] * 8]);
  };
  auto compute = [&](int buf) {
    const unsigned short* sA = smA + buf * (128 * 64);
    const unsigned short* sB = smB + buf * (128 * 64);
#pragma unroll
    for (int ks = 0; ks < 2; ++ks) {
      b8 aF[4], bF[4];
#pragma unroll
      for (int i = 0; i < 4; ++i) aF[i] = *(const b8*)&sA[aOff[i][ks]];
#pragma unroll
      for (int j = 0; j < 4; ++j) bF[j] = *(const b8*)&sB[bOff[j][ks]];
#pragma unroll
      for (int i = 0; i < 4; ++i)
#pragma unroll
        for (int j = 0; j < 4; ++j)
          acc[i][j] = __builtin_amdgcn_mfma_f32_16x16x32_bf16(aF[i], bF[j], acc[i][j], 0, 0, 0);
    }
  };

  stage(0, 0);
  __syncthreads();
  int cur = 0;
  for (int k0 = 64; k0 < 512; k0 += 64) {
    stage(cur ^ 1, k0);
    compute(cur);
    __syncthreads();
    cur ^= 1;
  }
  compute(cur);

  const int row0 = blockIdx.x * 128 + wr * 64 + fg * 4;
  const int col0 = blockIdx.y * 128 + wc * 64 + fm;
#pragma unroll
  for (int i = 0; i < 4; ++i) {
#pragma unroll
    for (int j = 0; j < 4; ++j) {
      const int col = col0 + j * 16;
      const float bv = bias[col];
#pragma unroll
      for (int r = 0; r < 4; ++r) {
        const int row = row0 + i * 16 + r;
        C[(long)row * 2048 + col] = f2bf(mishf(acc[i][j][r] + bv));
      }
    }
  }
}

// ---------------------------------------------------------------------------
// entmax 1.5 over rows of 1024 (in-place bf16). One wave per row.
// Candidate compaction (only z > m-1 can ever be in support), register fast
// paths for <=128 / <=256 candidates, LDS loop fallback. DPP reductions.
// ---------------------------------------------------------------------------
template <int NC>
DEV float solve_tau(const f32x2* zc, float tau) {
  int kprev = -1;
  const f32x2 zero2 = (f32x2){0.f, 0.f};
  for (int it = 0; it < 12; ++it) {
    const f32x2 t2 = (f32x2){tau, tau};
    f32x2 s1v = zero2, s2v = zero2;
    int k = 0;
#pragma unroll
    for (int i = 0; i < NC; ++i) {
      f32x2 h = zc[i] - t2;
      k += __popcll(__ballot(h.x > 0.f));
      k += __popcll(__ballot(h.y > 0.f));
      f32x2 hp = __builtin_elementwise_max(h, zero2);
      s1v += hp;
      s2v += hp * hp;
    }
    float s1 = wave_sum(s1v.x + s1v.y);
    float s2 = wave_sum(s2v.x + s2v.y);
    if (k == kprev) break;  // support fixed point -> tau exact (wave-uniform)
    kprev = k;
    float kf = (float)k;
    float disc = fmaxf(fmaf(s1, s1, -kf * (s2 - 1.f)), 0.f);
    tau += (s1 - __builtin_sqrtf(disc)) / kf;
  }
  return tau;
}

DEV float solve_tau_lds(const float* cw, int nch, int lane, float tau) {
  int kprev = -1;
  const f32x2 zero2 = (f32x2){0.f, 0.f};
  for (int it = 0; it < 12; ++it) {
    const f32x2 t2 = (f32x2){tau, tau};
    f32x2 s1v = zero2, s2v = zero2;
    int k = 0;
    for (int c = 0; c < nch; ++c) {
      f32x2 h = *(const f32x2*)&cw[c * 128 + lane * 2] - t2;
      k += __popcll(__ballot(h.x > 0.f));
      k += __popcll(__ballot(h.y > 0.f));
      f32x2 hp = __builtin_elementwise_max(h, zero2);
      s1v += hp;
      s2v += hp * hp;
    }
    float s1 = wave_sum(s1v.x + s1v.y);
    float s2 = wave_sum(s2v.x + s2v.y);
    if (k == kprev) break;
    kprev = k;
    float kf = (float)k;
    float disc = fmaxf(fmaf(s1, s1, -kf * (s2 - 1.f)), 0.f);
    tau += (s1 - __builtin_sqrtf(disc)) / kf;
  }
  return tau;
}

__global__ __launch_bounds__(256) void entmax_rows(unsigned short* __restrict__ P) {
  const int tid = threadIdx.x, lane = tid & 63, wv = tid >> 6;
  const long row = (long)blockIdx.x * 4 + wv;
  unsigned short* p = P + row * 1024;
  __shared__ float cand[4][1024];  // per-wave candidate buffer (16 KiB)

  union { uint4 v; unsigned short u[8]; } a, b;
  a.v = *(const uint4*)(p + lane * 16);
  b.v = *(const uint4*)(p + lane * 16 + 8);
  f32x2 zp[8];
#pragma unroll
  for (int i = 0; i < 4; ++i) {
    zp[i] = (f32x2){bf2f(a.u[2 * i]), bf2f(a.u[2 * i + 1])};
    zp[4 + i] = (f32x2){bf2f(b.u[2 * i]), bf2f(b.u[2 * i + 1])};
  }

  f32x2 mv = zp[0];
#pragma unroll
  for (int i = 1; i < 8; ++i) mv = __builtin_elementwise_max(mv, zp[i]);
  float m = wave_max(fmaxf(mv.x, mv.y));

  const float thr = m - 1.f;
  float* cw = cand[wv];

  // compact candidates (z > thr) into cw[0..base)
  int base = 0;
#pragma unroll
  for (int i = 0; i < 8; ++i) {
    unsigned long long mx = __ballot(zp[i].x > thr);
    if (zp[i].x > thr) cw[base + mbcnt64(mx)] = zp[i].x;
    base += __popcll(mx);
    unsigned long long my = __ballot(zp[i].y > thr);
    if (zp[i].y > thr) cw[base + mbcnt64(my)] = zp[i].y;
    base += __popcll(my);
  }

  // pad to a multiple of 128 with a value that never contributes
  const int nch = (base + 127) >> 7;  // 1..8 chunks of 128
  for (int i = base + lane; i < nch * 128; i += 64) cw[i] = -1e30f;

  float tau;
  if (nch == 1) {
    f32x2 zc[1];
    zc[0] = *(const f32x2*)&cw[lane * 2];
    tau = solve_tau<1>(zc, thr);
  } else if (nch == 2) {
    f32x2 zc[2];
    zc[0] = *(const f32x2*)&cw[lane * 2];
    zc[1] = *(const f32x2*)&cw[128 + lane * 2];
    tau = solve_tau<2>(zc, thr);
  } else {
    tau = solve_tau_lds(cw, nch, lane, thr);
  }

  const f32x2 t2 = (f32x2){tau, tau};
  const f32x2 zero2 = (f32x2){0.f, 0.f};
#pragma unroll
  for (int i = 0; i < 4; ++i) {
    f32x2 h0 = __builtin_elementwise_max(zp[i] - t2, zero2);
    f32x2 h1 = __builtin_elementwise_max(zp[4 + i] - t2, zero2);
    f32x2 p0 = h0 * h0, p1 = h1 * h1;
    a.u[2 * i] = f2bf(p0.x);
    a.u[2 * i + 1] = f2bf(p0.y);
    b.u[2 * i] = f2bf(p1.x);
    b.u[2 * i + 1] = f2bf(p1.y);
  }
  *(uint4*)(p + lane * 16) = a.v;
  *(uint4*)(p + lane * 16 + 8) = b.v;
}

// ---------------------------------------------------------------------------
// Merged prep: x cast + 6 weight transposes + bias concat in ONE launch.
// ---------------------------------------------------------------------------
__global__ __launch_bounds__(256) void prep_all(
    const float* __restrict__ x, unsigned short* __restrict__ xb,
    const float* __restrict__ Wq, const float* __restrict__ Wk,
    const float* __restrict__ Wv, const float* __restrict__ Wo,
    const float* __restrict__ W1, const float* __restrict__ W2,
    unsigned short* __restrict__ Wqkvt, unsigned short* __restrict__ Wot,
    unsigned short* __restrict__ W1t, unsigned short* __restrict__ W2t,
    const float* __restrict__ bq, const float* __restrict__ bk,
    const float* __restrict__ bv, float* __restrict__ bqkv) {
  __shared__ float t[32][33];
  const int bid = blockIdx.x, tid = threadIdx.x;

  if (bid < 4096) {  // cast x -> bf16, 4 elems/thread
    long i = ((long)bid * 256 + tid) * 4;
    float4 v = *(const float4*)&x[i];
    uint2 pk;
    pk.x = (unsigned)f2bf(v.x) | ((unsigned)f2bf(v.y) << 16);
    pk.y = (unsigned)f2bf(v.z) | ((unsigned)f2bf(v.w) << 16);
    *(uint2*)&xb[i] = pk;
    return;
  }

  const float* in;
  unsigned short* out;
  int ldi, ldo, bx, by;
  if (bid < 5120) {
    int t4 = (bid - 4096) >> 8, local = (bid - 4096) & 255;
    const float* ins[4] = {Wq, Wk, Wv, Wo};
    unsigned short* outs[4] = {Wqkvt, Wqkvt + 512 * 512, Wqkvt + 2 * 512 * 512, Wot};
    in = ins[t4];
    out = outs[t4];
    ldi = 512;
    ldo = 512;
    bx = local & 15;
    by = local >> 4;
  } else if (bid < 6144) {
    int local = bid - 5120;  // W1 [512][2048] -> W1t [2048][512]
    in = W1;
    out = W1t;
    ldi = 2048;
    ldo = 512;
    bx = local & 63;
    by = local >> 6;
  } else if (bid < 7168) {
    int local = bid - 6144;  // W2 [2048][512] -> W2t [512][2048]
    in = W2;
    out = W2t;
    ldi = 512;
    ldo = 2048;
    bx = local & 15;
    by = local >> 4;
  } else {  // concat biases
    int i = (bid - 7168) * 256 + tid;
    if (i < 512) bqkv[i] = bq[i];
    else if (i < 1024) bqkv[i] = bk[i - 512];
    else if (i < 1536) bqkv[i] = bv[i - 1024];
    return;
  }

  const int tx = tid & 31, ty = tid >> 5;
  const int r0 = by * 32, c0 = bx * 32;
#pragma unroll
  for (int q = 0; q < 4; ++q) {
    int r = ty + q * 8;
    t[r][tx] = in[(long)(r0 + r) * ldi + c0 + tx];
  }
  __syncthreads();
#pragma unroll
  for (int q = 0; q < 4; ++q) {
    int r = ty + q * 8;
    out[(long)(c0 + r) * ldo + r0 + tx] = f2bf(t[tx][r]);
  }
}

// bf16 batched transpose (for V -> V^T per (b,h))
__global__ __launch_bounds__(256) void transpose_b2b(const unsigned short* __restrict__ in,
                                                     unsigned short* __restrict__ out,
                                                     int ldi, int ldo, long i1, long i2,
                                                     long o1, long o2, int hdiv) {
  __shared__ unsigned short t[32][33];
  const int z = blockIdx.z;
  in += (long)(z / hdiv) * i1 + (long)(z % hdiv) * i2;
  out += (long)(z / hdiv) * o1 + (long)(z % hdiv) * o2;
  const int tx = threadIdx.x & 31, ty = threadIdx.x >> 5;
  const int r0 = blockIdx.y * 32, c0 = blockIdx.x * 32;
#pragma unroll
  for (int q = 0; q < 4; ++q) {
    int r = ty + q * 8;
    t[r][tx] = in[(long)(r0 + r) * ldi + c0 + tx];
  }
  __syncthreads();
#pragma unroll
  for (int q = 0; q < 4; ++q) {
    int r = ty + q * 8;
    out[(long)(c0 + r) * ldo + r0 + tx] = t[tx][r];
  }
}

// ---------------------------------------------------------------------------
// out = xin + LayerNorm(sum_j y[j*ystr] + ybias)*g + be   (row 512)
// ---------------------------------------------------------------------------
template <bool WB, int NS>
__global__ __launch_bounds__(256) void ln_res(const float* __restrict__ xin,
                                              const float* __restrict__ y, long ystr,
                                              const float* __restrict__ ybias,
                                              const float* __restrict__ g,
                                              const float* __restrict__ be,
                                              float* __restrict__ xo,
                                              unsigned short* __restrict__ xob) {
  const int row = blockIdx.x, tid = threadIdx.x, lane = tid & 63, wv = tid >> 6;
  const long base = (long)row * 512 + tid * 2;
  const int c = tid * 2;
  float2 v = *(const float2*)&y[base];
#pragma unroll
  for (int j = 1; j < NS; ++j) {
    float2 u = *(const float2*)&y[base + j * ystr];
    v.x += u.x;
    v.y += u.y;
  }
  v.x += ybias[c];
  v.y += ybias[c + 1];
  float s1 = wave_sum(v.x + v.y);
  float s2 = wave_sum(v.x * v.x + v.y * v.y);
  __shared__ float red[4][2];
  if (lane == 0) {
    red[wv][0] = s1;
    red[wv][1] = s2;
  }
  __syncthreads();
  s1 = red[0][0] + red[1][0] + red[2][0] + red[3][0];
  s2 = red[0][1] + red[1][1] + red[2][1] + red[3][1];
  const float mu = s1 * (1.f / 512.f);
  const float rstd = rsqrtf(s2 * (1.f / 512.f) - mu * mu + 1e-5f);
  float2 xv = *(const float2*)&xin[base];
  float o0 = xv.x + (v.x - mu) * rstd * g[c] + be[c];
  float o1 = xv.y + (v.y - mu) * rstd * g[c + 1] + be[c + 1];
  float2 ov;
  ov.x = o0;
  ov.y = o1;
  *(float2*)&xo[base] = ov;
  if constexpr (WB) {
    unsigned pk = (unsigned)f2bf(o0) | ((unsigned)f2bf(o1) << 16);
    *(unsigned*)&xob[base] = pk;
  }
}

// ---------------------------------------------------------------------------
extern "C" void kernel_launch(void* const* d_in, const int* in_sizes, int n_in,
                              void* d_out, int out_size, void* d_ws, size_t ws_size,
                              hipStream_t stream) {
  const int B = 8, S = 1024, D = 512, H = 8, F = 2048;
  const int BS = B * S;  // 8192 rows
  const int N3 = 3 * D;  // 1536

  const float* x = (const float*)d_in[0];
  const float* Wq = (const float*)d_in[1];
  const float* bq = (const float*)d_in[2];
  const float* Wk = (const float*)d_in[3];
  const float* bk = (const float*)d_in[4];
  const float* Wv = (const float*)d_in[5];
  const float* bv = (const float*)d_in[6];
  const float* Wo = (const float*)d_in[7];
  const float* bo = (const float*)d_in[8];
  const float* g1 = (const float*)d_in[9];
  const float* be1 = (const float*)d_in[10];
  const float* W1 = (const float*)d_in[11];
  const float* b1 = (const float*)d_in[12];
  const float* W2 = (const float*)d_in[13];
  const float* b2 = (const float*)d_in[14];
  const float* g2 = (const float*)d_in[15];
  const float* be2 = (const float*)d_in[16];
  float* out = (float*)d_out;

  char* w = (char*)d_ws;
  size_t off = 0;
  auto alloc = [&](size_t bytes) -> void* {
    void* p = w + off;
    off += bytes;
    off = (off + 255) & ~(size_t)255;
    return p;
  };

  unsigned short* xb = (unsigned short*)alloc((size_t)BS * D * 2);
  unsigned short* Wqkvt = (unsigned short*)alloc((size_t)N3 * D * 2);
  unsigned short* Wot = (unsigned short*)alloc((size_t)D * D * 2);
  unsigned short* W1t = (unsigned short*)alloc((size_t)F * D * 2);
  unsigned short* W2t = (unsigned short*)alloc((size_t)D * F * 2);
  float* bqkv = (float*)alloc((size_t)N3 * 4);
  unsigned short* QKVb = (unsigned short*)alloc((size_t)BS * N3 * 2);
  unsigned short* Vt = (unsigned short*)alloc((size_t)BS * D * 2);
  unsigned short* attn = (unsigned short*)alloc((size_t)BS * D * 2);
  unsigned short* P = (unsigned short*)alloc((size_t)B * H * S * S * 2);  // 128 MiB
  float* x1 = (float*)alloc((size_t)BS * D * 4);
  unsigned short* hb = (unsigned short*)alloc((size_t)BS * F * 2);
  unsigned short* x1b = xb;   // reuse: xb dead after QKV GEMM
  float* yp = (float*)P;      // reuse: P dead after PV GEMM
  const long PSTR = (long)BS * D;

  const long SS = (long)S * S;
  const long HSS = (long)H * SS;

  // 1) merged prep: cast x, transpose all weights, concat qkv bias
  prep_all<<<7174, 256, 0, stream>>>(x, xb, Wq, Wk, Wv, Wo, W1, W2,
                                     Wqkvt, Wot, W1t, W2t, bq, bk, bv, bqkv);

  // 2) merged QKV projection: [8192][1536] bf16
  gemm_bt<2, 2, 1, true><<<dim3(BS / 128, N3 / 128, 1), 256, 0, stream>>>(
      xb, Wqkvt, bqkv, QKVb, D, D, D, N3, 0, 0, 0, 0, 0, 0, 1, 1.f);

  // 3) V -> Vt[(b,h), d, s]
  transpose_b2b<<<dim3(2, 32, 64), 256, 0, stream>>>(
      QKVb + 1024, Vt, N3, S, (long)S * N3, 64, (long)8 * 64 * S, (long)64 * S, 8);

  // 4) scores z = (Q K^T)/16 -> P bf16   (Q at col 0, K at col 512 of QKVb)
  gemm_bt<2, 2, 0, true><<<dim3(S / 128, S / 128, B * H), 256, 0, stream>>>(
      QKVb, QKVb + 512, nullptr, P, 64, N3, N3, S,
      (long)S * N3, 64, (long)S * N3, 64, HSS, SS, H, 1.f / 16.f);

  // 5) entmax-1.5 per row, in place (candidate-compacted support iteration)
  entmax_rows<<<(B * H * S) / 4, 256, 0, stream>>>(P);

  // 6) attn = P @ V   (256x64 tiles)
  gemm_bt<4, 1, 0, true><<<dim3(S / 256, 1, B * H), 256, 0, stream>>>(
      P, Vt, nullptr, attn, S, S, S, D,
      HSS, SS, (long)8 * 64 * S, (long)64 * S, (long)S * D, 64, H, 1.f);

  // 7) y = attn @ Wo, split-K x2 (bias folded into ln_res)
  gemm_bt<2, 2, 0, false><<<dim3(BS / 128, D / 128, 2), 256, 0, stream>>>(
      attn, Wot, nullptr, yp, D / 2, D, D, D, 0, D / 2, 0, D / 2, 0, PSTR, 2, 1.f);

  // 8) x1 = x + LN(y0+y1+bo)*g1 + be1
  ln_res<true, 2><<<BS, 256, 0, stream>>>(x, yp, PSTR, bo, g1, be1, x1, x1b);

  // 9) h = mish(x1 @ W1 + b1) (bf16) - standalone dbuf kernel
  gemm_ffn1<<<dim3(BS / 128, F / 128, 1), 256, 0, stream>>>(x1b, W1t, b1, hb);

  // 10) y2 = h @ W2, split-K x2 (K-chunks of 1024)
  gemm_bt<2, 2, 0, false><<<dim3(BS / 128, D / 128, 2), 256, 0, stream>>>(
      hb, W2t, nullptr, yp, F / 2, F, F, D, 0, F / 2, 0, F / 2, 0, PSTR, 2, 1.f);

  // 11) out = x1 + LN(y0+y1+b2)*g2 + be2
  ln_res<false, 2><<<BS, 256, 0, stream>>>(x1, yp, PSTR, b2, g2, be2, out, nullptr);
}